// Round 13
// baseline (2222.774 us; speedup 1.0000x reference)
//
#include <hip/hip_runtime.h>
#include <math.h>

// ---------------------------------------------------------------------------
// S2ConvNet_deep: 7 spectral conv layers (1 S2 + 6 SO3) + SO3-integrate + MLP.
// All constant tables computed on-device every call (graph-capture safe).
// R1: z_so3 as LDS-tiled complex GEMM.          R2: fused output synth.
// R3: Hermitian synth (m>=0 rows).              R4: register-resident P2.
// R5: streaming G-build + Hermitian input halving (m>=0 alpha freqs).
// R6: gamma-Hermitian dft2h.                    R8: dft_r real pass-1 DFT.
// R7: synth2_t (N=60) 2 waves/plane.            R9: radix-2 DIF + a-fold.
// R10: DIF+fold in synth_t; wigner dedup.       R11: 1 wigner launch; kf inline.
// R12: (a) synth2 G-build uses LDS atomicAdd (ds_add_f32) -> ZERO per-l
//      barriers (was 30) and 1 LDS op per update instead of dependent RMW;
//      (b) din tables stored j-minor ([e][j]) so xh's 60-j gather is
//      contiguous per thread (was 18KB-strided, 3840 lines/wave). Aliased
//      L3/5/7 read the j-major dout via eMul/jMul addressing. R11 showed
//      launch count is irrelevant (56->43 was exactly neutral).
// ---------------------------------------------------------------------------

#define DFT_LDS 3712   // float2 slots for DFT staging (29.7 KB)

__host__ __device__ inline long long SF(int l) { return (long long)l * (4LL*l*l - 1) / 3; }
__device__ inline int imod(int a, int n) { int r = a % n; return r < 0 ? r + n : r; }

// ---------------- Wigner small-d, ALL tables in one launch (fp64) -----------
struct WigCfg {
    int nseg;
    int nblk[16];
    int off[16];        // float offset into ws
    int b_out[16];
    int colmode[16];    // 1 = column m=0 only (S2 din), 0 = full
    int jmaj[16];       // 1 = store [e][j] (j-minor) for coalesced xh reads
    int nb[16];         // n_beta of segment
    double beta0[16];
    double bstep[16];
};

__global__ void wigner_all_kernel(float* __restrict__ ws, WigCfg cfg)
{
    __shared__ double lf[128];
    for (int t = threadIdx.x; t < 128; t += blockDim.x) lf[t] = lgamma((double)t + 1.0);
    __syncthreads();

    int b = blockIdx.x, s = 0;
    while (b >= cfg.nblk[s]) { b -= cfg.nblk[s]; s++; }
    float* out = ws + cfg.off[s];
    int b_out = cfg.b_out[s];
    int colmode = cfg.colmode[s];
    int jm = cfg.jmaj[s];
    int nb = cfg.nb[s];
    int l = b % b_out, j = b / b_out;
    double beta = cfg.beta0[s] + cfg.bstep[s] * j;

    double x  = cos(beta);
    double sb = sin(0.5 * beta);
    double cb = cos(0.5 * beta);
    double lsb = log(sb), lcb = log(cb);
    int dim = 2*l + 1;
    long long S  = SF(b_out);
    long long Ol = SF(l);
    long long b2 = (long long)b_out * b_out;
    int total = colmode ? dim : dim * dim;
    for (int t = threadIdx.x; t < total; t += blockDim.x) {
        int mi, ni;
        if (colmode) { mi = t; ni = l; }
        else         { mi = t / dim; ni = t % dim; }
        int mp = mi - l, mm = ni - l;
        int k1 = l + mm, k2 = l - mm, k3 = l + mp, k4 = l - mp;
        int kk = min(min(k1, k2), min(k3, k4));
        int a, lam;
        if      (kk == k1) { a = mp - mm; lam = mp - mm; }
        else if (kk == k2) { a = mm - mp; lam = 0; }
        else if (kk == k3) { a = mm - mp; lam = 0; }
        else               { a = mp - mm; lam = mp - mm; }
        int bb = 2*l - 2*kk - a;
        double lpref = 0.5 * (lf[2*l - kk] + lf[kk] - lf[kk + a] - lf[kk + bb]);
        double P = 1.0;
        if (kk >= 1) {
            double p0 = 1.0;
            double p1 = 0.5 * ((double)(a - bb) + (double)(a + bb + 2) * x);
            for (int n = 2; n <= kk; n++) {
                double c1 = 2.0*n*(n + a + bb)*(2.0*n + a + bb - 2.0);
                double c2 = (2.0*n + a + bb - 1.0) *
                            ((2.0*n + a + bb)*(2.0*n + a + bb - 2.0)*x + (double)(a*a) - (double)(bb*bb));
                double c3 = 2.0*(n + a - 1.0)*(n + bb - 1.0)*(2.0*n + a + bb);
                double pn = (c2*p1 - c3*p0) / c1;
                p0 = p1; p1 = pn;
            }
            P = p1;
        }
        double val = exp(lpref + (double)a * lsb + (double)bb * lcb) * P;
        if (lam & 1) val = -val;
        long long e = colmode ? ((long long)l*l + mi) : (Ol + (long long)mi * dim + ni);
        long long idx;
        if (jm) idx = e * nb + j;
        else    idx = colmode ? ((long long)j * b2 + e) : ((long long)j * S + e);
        out[idx] = (float)val;
    }
}

// ---------------- setup: twiddles + DH weights in one launch ----------------
__global__ void setup_kernel(float2* __restrict__ W, float* __restrict__ w)
{
    int t = threadIdx.x + blockIdx.x * blockDim.x;
    if (t >= 110) return;
    const int Ns[4]   = {60, 30, 14, 6};
    const int offs[4] = {0, 60, 90, 104};
    int si = (t < 60) ? 0 : (t < 90) ? 1 : (t < 104) ? 2 : 3;
    int N = Ns[si];
    int k = t - offs[si];
    double ang = -2.0 * M_PI * (double)k / (double)N;
    W[t] = make_float2((float)cos(ang), (float)sin(ang));
    int b = N / 2;
    double beta = M_PI * (2*k + 1) / (4.0 * b);
    double s = 0.0;
    for (int kk = 0; kk < b; kk++) s += sin((2*kk + 1) * beta) / (2*kk + 1);
    w[t] = (float)((2.0 / b) * sin(beta) * s);
}

// ---------------- real-input forward DFT: [R, N] reals -> [R, NF] ----------
__global__ void dft_r_kernel(const float* __restrict__ in, float2* __restrict__ out,
                             const float2* __restrict__ Wt,
                             int R, int N, int NF, int RPB)
{
    __shared__ float s[2 * DFT_LDS];
    __shared__ float2 sW[64];
    int r0 = blockIdx.x * RPB;
    if (r0 >= R) return;
    int nr = min(RPB, R - r0);
    for (int t = threadIdx.x; t < N; t += blockDim.x) sW[t] = Wt[t];
    for (int t = threadIdx.x; t < nr * N; t += blockDim.x)
        s[t] = in[(long long)r0 * N + t];
    __syncthreads();
    for (int t = threadIdx.x; t < nr * NF; t += blockDim.x) {
        int rr = t / NF, f = t % NF;
        const float* row = s + rr * N;
        float re = 0.f, im = 0.f;
        int tw = 0;
        for (int n = 0; n < N; n++) {
            float2 w = sW[tw];
            float v = row[n];
            re += v * w.x;
            im += v * w.y;
            tw += f; if (tw >= N) tw -= N;
        }
        out[(long long)(r0 + rr) * NF + f] = make_float2(re, im);
    }
}

// ---------------- pass-2 alpha DFT with Hermitian gamma reconstruction ------
__global__ void dft2h_kernel(const float2* __restrict__ in, float2* __restrict__ out,
                             const float2* __restrict__ Wt,
                             int R, int N, int C2, int RPB)
{
    __shared__ float2 s[DFT_LDS];
    __shared__ float2 sW[64];
    int r0 = blockIdx.x * RPB;
    if (r0 >= R) return;
    int nr = min(RPB, R - r0);
    int slab = N * C2;
    for (int t = threadIdx.x; t < N; t += blockDim.x) sW[t] = Wt[t];
    for (int t = threadIdx.x; t < nr * slab; t += blockDim.x)
        s[t] = in[(long long)r0 * slab + t];
    __syncthreads();
    int M = 2 * C2 - 1;
    int oslab = C2 * M;
    int work = C2 * C2;
    for (int t = threadIdx.x; t < nr * work; t += blockDim.x) {
        int rr = t / work, p = t % work;
        int m = p / C2, npos = p % C2;
        const float2* col = s + rr * slab + npos;
        float r1 = 0.f, i1 = 0.f, r2 = 0.f, i2 = 0.f;
        int tw = 0;
        for (int n = 0; n < N; n++) {
            float2 w = sW[tw];
            float2 v = col[n * C2];
            r1 += v.x * w.x - v.y * w.y;
            i1 += v.x * w.y + v.y * w.x;
            r2 += v.x * w.x + v.y * w.y;
            i2 += v.y * w.x - v.x * w.y;
            tw += m; if (tw >= N) tw -= N;
        }
        float2* ob = out + (long long)(r0 + rr) * oslab + (long long)m * M;
        ob[(C2 - 1) + npos] = make_float2(r1, i1);
        if (npos > 0) ob[(C2 - 1) - npos] = make_float2(r2, -i2);
    }
}

// ---------------- xh (Wigner analysis of input), rows mi >= l only ----------
// din addressing: din[e * eMul + j * jMul] (supports j-minor and j-major).
__global__ void xh_so3_kernel(const float2* __restrict__ xf, const float* __restrict__ din,
                              const float* __restrict__ wq, float2* __restrict__ xh,
                              int B, int Ci, int Nin, int b_out, int eMul, int jMul)
{
    int l = blockIdx.y;
    int dim = 2*l + 1;
    int M = 2*b_out - 1;
    long long S = SF(b_out), Ol = SF(l);
    int rows = l + 1;
    int total = B * Ci * rows * dim;
    int idx = blockIdx.x * blockDim.x + threadIdx.x;
    if (idx >= total) return;
    int ni  = idx % dim;
    int mip = (idx / dim) % rows;
    int bc  = idx / (dim * rows);
    int mi  = mip + l;
    int mf  = mip;
    int nf  = ni - l + (b_out - 1);
    float re = 0.f, im = 0.f;
    const float2* xb = xf + ((long long)bc * Nin) * b_out * M + (long long)mf * M + nf;
    const float*  db = din + (Ol + (long long)mi * dim + ni) * eMul;
    for (int j = 0; j < Nin; j++) {
        float dv = db[(long long)j * jMul] * wq[j];
        float2 xv = xb[(long long)j * b_out * M];
        re += dv * xv.x; im += dv * xv.y;
    }
    xh[(long long)bc * S + Ol + (long long)mi * dim + ni] = make_float2(re, im);
}

__global__ void xh_s2_kernel(const float2* __restrict__ xf, const float* __restrict__ dincol,
                             const float* __restrict__ wq, float2* __restrict__ xh,
                             int B, int Ci, int Nin, int b_out, int eMul, int jMul)
{
    int l = blockIdx.y;
    int b2 = b_out * b_out;
    int rows = l + 1;
    int total = B * Ci * rows;
    int idx = blockIdx.x * blockDim.x + threadIdx.x;
    if (idx >= total) return;
    int mip = idx % rows;
    int bc  = idx / rows;
    int mi  = mip + l;
    int mf  = mip;
    const float* db = dincol + ((long long)l*l + mi) * eMul;
    float re = 0.f, im = 0.f;
    for (int j = 0; j < Nin; j++) {
        float dv = db[(long long)j * jMul] * wq[j];
        float2 xv = xf[((long long)bc * Nin + j) * b_out + mf];
        re += dv * xv.x; im += dv * xv.y;
    }
    xh[(long long)bc * b2 + (long long)l*l + mi] = make_float2(re, im);
}

// ---------------- Y = dg * kf (kf inlined): per l, [i][ki][o*dim+ni] --------
__global__ void y_so3_direct(const float* __restrict__ kw, const float* __restrict__ dg,
                             float2* __restrict__ Y, int Ci, int Co, int b_out)
{
    const float cr[6] = {1.f, .5f, -.5f, -1.f, -.5f, .5f};
    const float ci_[6] = {0.f, -0.8660254037844386f, -0.8660254037844386f, 0.f,
                          0.8660254037844386f, 0.8660254037844386f};
    int l = blockIdx.y;
    int dim = 2*l + 1;
    long long Ol = SF(l);
    int Nd = Co * dim;
    int total = Ci * dim * Nd;
    int idx = blockIdx.x * blockDim.x + threadIdx.x;
    if (idx >= total) return;
    int col  = idx % Nd;
    int krow = idx / Nd;
    int ki = krow % dim, i = krow / dim;
    int o  = col / dim,  ni = col % dim;
    float dgv = dg[Ol + (long long)ni * dim + ki];
    int m = ni - l, n = ki - l;
    const float* kb = kw + (long long)(i*Co + o) * 36;
    int step = imod(2 * n, 6);
    float re = 0.f, im = 0.f;
    for (int a = 0; a < 6; a++) {
        int tt = imod(a * (m - n), 6);
        #pragma unroll
        for (int g = 0; g < 6; g++) {
            float kv = kb[a*6 + g];
            re += kv * cr[tt]; im += kv * ci_[tt];
            tt += step; if (tt >= 6) tt -= 6;
        }
    }
    Y[(long long)Ci * Co * Ol + idx] = make_float2(dgv * re, dgv * im);
}

// ---------------- z = xh · conj(Y), rows mi >= l only -----------------------
__global__ void z_so3_gemm(const float2* __restrict__ xh, const float2* __restrict__ Y,
                           float2* __restrict__ z, int B, int Ci, int Co, int b_out)
{
    int l = blockIdx.z;
    int dim = 2*l + 1;
    int rows = l + 1;
    long long S = SF(b_out), Ol = SF(l);
    int Nd = Co * dim;
    int c0 = blockIdx.x * 64;
    if (c0 >= Nd) return;
    int b = blockIdx.y;
    int tid = threadIdx.x;
    int cc = tid & 63;
    int mg = tid >> 6;
    int col = c0 + cc;
    __shared__ float2 sA[32 * 29];
    __shared__ float2 sY[29 * 64];
    float2 acc[8];
    #pragma unroll
    for (int r = 0; r < 8; r++) acc[r] = make_float2(0.f, 0.f);
    const float2* Yl = Y + (long long)Ci * Co * Ol;
    int rd = rows * dim;
    for (int i = 0; i < Ci; i++) {
        const float2* Ab = xh + ((long long)(b*Ci + i)) * S + Ol + (long long)l * dim;
        for (int t = tid; t < 32 * dim; t += 256)
            sA[t] = (t < rd) ? Ab[t] : make_float2(0.f, 0.f);
        const float2* Yb = Yl + (long long)i * dim * Nd;
        for (int t = tid; t < dim * 64; t += 256) {
            int ki = t >> 6, c = t & 63;
            int gc = c0 + c;
            sY[t] = (gc < Nd) ? Yb[(long long)ki * Nd + gc] : make_float2(0.f, 0.f);
        }
        __syncthreads();
        for (int ki = 0; ki < dim; ki++) {
            float2 y = sY[ki*64 + cc];
            #pragma unroll
            for (int r = 0; r < 8; r++) {
                if (r*4 + mg < rows) {
                    float2 a = sA[(r*4 + mg) * dim + ki];
                    acc[r].x += a.x * y.x + a.y * y.y;
                    acc[r].y += a.y * y.x - a.x * y.y;
                }
            }
        }
        __syncthreads();
    }
    if (col < Nd) {
        int o = col / dim, ni = col % dim;
        long long base = ((long long)(b*Co + o)) * S + Ol + ni;
        #pragma unroll
        for (int r = 0; r < 8; r++) {
            int mip = r*4 + mg;
            if (mip < rows) z[base + (long long)(mip + l) * dim] = acc[r];
        }
    }
}

// ---------------- z for S2 layer (kf inlined, Ci small) ---------------------
__global__ void z_s2_direct(const float2* __restrict__ xh, const float* __restrict__ kw,
                            const float* __restrict__ dg, float2* __restrict__ z,
                            int B, int Ci, int Co, int b_out)
{
    const float cr[6] = {1.f, .5f, -.5f, -1.f, -.5f, .5f};
    const float ci_[6] = {0.f, -0.8660254037844386f, -0.8660254037844386f, 0.f,
                          0.8660254037844386f, 0.8660254037844386f};
    int l = blockIdx.y;
    int dim = 2*l + 1;
    int b2 = b_out * b_out;
    int rows = l + 1;
    long long S = SF(b_out), Ol = SF(l);
    int total = B * Co * rows * dim;
    int idx = blockIdx.x * blockDim.x + threadIdx.x;
    if (idx >= total) return;
    int ni  = idx % dim;
    int mip = (idx / dim) % rows;
    int o   = (idx / (dim * rows)) % Co;
    int b   = idx / (dim * rows * Co);
    int mi  = mip + l;
    float dgv = dg[Ol + (long long)ni * dim + l];
    int m = ni - l;
    int step = imod(m, 6);
    float sre = 0.f, sim = 0.f;
    for (int i = 0; i < Ci; i++) {
        const float* kb = kw + (long long)(i*Co + o) * 6;
        float kre = 0.f, kim = 0.f;
        int tt = 0;
        #pragma unroll
        for (int p = 0; p < 6; p++) {
            float kv = kb[p];
            kre += kv * cr[tt]; kim += kv * ci_[tt];
            tt += step; if (tt >= 6) tt -= 6;
        }
        float2 xv = xh[(long long)(b*Ci + i) * b2 + (long long)l*l + mi];
        sre += xv.x * kre + xv.y * kim;
        sim += xv.y * kre - xv.x * kim;
    }
    z[((long long)(b*Co + o)) * S + Ol + (long long)mi * dim + ni] = make_float2(dgv * sre, dgv * sim);
}

// ---------------- fused Hermitian output synthesis (R10: DIF+fold) ----------
template<int N, int ROWS, int GS, int PPB, int BLK>
__global__ __launch_bounds__(BLK) void synth_t(
    const float2* __restrict__ z, const float* __restrict__ dout,
    const float2* __restrict__ Wt, float* __restrict__ act, int nPlanes)
{
    __shared__ float2 sP1[PPB][ROWS * N];
    __shared__ float2 sW[N];
    int tid = threadIdx.x;
    for (int t = tid; t < N; t += BLK) sW[t] = Wt[t];
    int lane = tid & 63, wave = tid >> 6;
    int sub = lane / GS, g = lane - sub * GS;
    int lp = wave * (64 / GS) + sub;
    int P = blockIdx.x * PPB + lp;
    bool on = (P < nPlanes);
    int bo = on ? (P / N) : 0, j = on ? (P - (P / N) * N) : 0;
    long long S = SF(ROWS);
    const float* dj = dout + (long long)j * S;
    const float2* zb = z + (long long)bo * S;
    float2* P1 = sP1[lp];
    for (int t = g; t < ROWS * N; t += GS) P1[t] = make_float2(0.f, 0.f);
    if (on) {
        for (int l = 0; l < ROWS; l++) {
            int dim = 2*l + 1;
            int run = (l + 1) * dim;
            long long base = SF(l) + (long long)l * dim;
            float fdim = (float)dim;
            float rdim = 1.f / fdim;
            for (int s0 = 0; s0 < run; s0 += GS) {
                int s = s0 + g;
                if (s < run) {
                    int m = (int)((float)s * rdim);
                    int rem = s - m * dim;
                    if (rem < 0)         { m--; rem += dim; }
                    else if (rem >= dim) { m++; rem -= dim; }
                    int q = rem - l; if (q < 0) q += N;
                    long long e = base + s;
                    float dv = dj[e] * fdim;
                    float2 zv = zb[e];
                    float2 cur = P1[m * N + q];
                    cur.x += dv * zv.x; cur.y += dv * zv.y;
                    P1[m * N + q] = cur;
                }
            }
        }
    }
    __syncthreads();
    if (on) {
        for (int t = g; t < ROWS * (N/2); t += GS) {
            int mm = t / (N/2), qp = t - mm * (N/2);
            int row = mm * N;
            float2 a = P1[row + qp];
            float2 b = P1[row + qp + N/2];
            float2 w = sW[qp];
            float2 d = make_float2(a.x - b.x, a.y - b.y);
            P1[row + qp]       = make_float2(a.x + b.x, a.y + b.y);
            P1[row + qp + N/2] = make_float2(d.x * w.x + d.y * w.y,
                                             d.y * w.x - d.x * w.y);
        }
    }
    __syncthreads();
    float2 acc[ROWS];
    #pragma unroll
    for (int m = 0; m < ROWS; m++) acc[m] = make_float2(0.f, 0.f);
    bool act_ = on && (g < N);
    if (act_) {
        int par = g & 1, gp = g >> 1;
        int off = par * (N/2);
        float2 wv = make_float2(1.f, 0.f);
        float2 wg = sW[2 * gp]; wg.y = -wg.y;
        for (int qp = 0; qp < N/2; qp++) {
            #pragma unroll
            for (int m = 0; m < ROWS; m++) {
                float2 v = P1[m * N + off + qp];
                acc[m].x += v.x * wv.x - v.y * wv.y;
                acc[m].y += v.x * wv.y + v.y * wv.x;
            }
            float nx = wv.x * wg.x - wv.y * wg.y;
            wv.y = wv.x * wg.y + wv.y * wg.x;
            wv.x = nx;
        }
    }
    if (!act_) return;
    float* ob = act + ((long long)bo * N + j) * (N * N);
    for (int a = 0; a < N/2; a++) {
        float se = 0.f, so = 0.f;
        int t0 = 0;
        #pragma unroll
        for (int m = 1; m < ROWS; m++) {
            t0 += a; if (t0 >= N) t0 -= N;
            float vx = acc[m].x + acc[m].x;
            float vy = acc[m].y + acc[m].y;
            float2 w0 = sW[t0];
            float term = vx * w0.x + vy * w0.y;
            if (m & 1) so += term; else se += term;
        }
        float base = acc[0].x;
        ob[a * N + g]         = fmaxf(base + se + so, 0.f);
        ob[(a + N/2) * N + g] = fmaxf(base + se - so, 0.f);
    }
}

// ---------------- 2-wave synth for N=60 (R12: atomic G-build) ---------------
template<int N, int ROWS, int HALF>
__global__ __launch_bounds__(128) void synth2_t(
    const float2* __restrict__ z, const float* __restrict__ dout,
    const float2* __restrict__ Wt, float* __restrict__ act, int nPlanes)
{
    __shared__ float2 sP1[ROWS * N];
    __shared__ float2 sW[N];
    int tid = threadIdx.x;
    for (int t = tid; t < N; t += 128) sW[t] = Wt[t];
    int lane = tid & 63, wave = tid >> 6;
    int g = lane;
    int P = blockIdx.x;
    if (P >= nPlanes) return;            // block-uniform
    int bo = P / N, j = P - bo * N;
    long long S = SF(ROWS);
    const float* dj = dout + (long long)j * S;
    const float2* zb = z + (long long)bo * S;
    for (int t = tid; t < ROWS * N; t += 128) sP1[t] = make_float2(0.f, 0.f);
    __syncthreads();
    // ---- G build: all 128 threads, LDS float atomics, NO per-l barrier ----
    float* P1f = (float*)sP1;
    for (int l = 0; l < ROWS; l++) {
        int dim = 2*l + 1;
        int run = (l + 1) * dim;
        long long base = SF(l) + (long long)l * dim;
        float fdim = (float)dim;
        float rdim = 1.f / fdim;
        for (int s0 = 0; s0 < run; s0 += 128) {
            int s = s0 + tid;
            if (s < run) {
                int m = (int)((float)s * rdim);
                int rem = s - m * dim;
                if (rem < 0)         { m--; rem += dim; }
                else if (rem >= dim) { m++; rem -= dim; }
                int q = rem - l; if (q < 0) q += N;
                long long e = base + s;
                float dv = dj[e] * fdim;
                float2 zv = zb[e];
                atomicAdd(&P1f[2 * (m * N + q)],     dv * zv.x);
                atomicAdd(&P1f[2 * (m * N + q) + 1], dv * zv.y);
            }
        }
    }
    __syncthreads();
    // ---- radix-2 DIF pre-transform on own rows ----
    int m0 = wave * HALF;
    for (int t = lane; t < HALF * (N/2); t += 64) {
        int mm = t / (N/2), qp = t - mm * (N/2);
        int row = (m0 + mm) * N;
        float2 a = sP1[row + qp];
        float2 b = sP1[row + qp + N/2];
        float2 w = sW[qp];
        float2 d = make_float2(a.x - b.x, a.y - b.y);
        sP1[row + qp]       = make_float2(a.x + b.x, a.y + b.y);
        sP1[row + qp + N/2] = make_float2(d.x * w.x + d.y * w.y,
                                          d.y * w.x - d.x * w.y);
    }
    __syncthreads();
    // ---- q-pass: thread g -> parity p = g&1, k' = g>>1; 30-pt DFT ----
    if (g < N) {
        float2 acc[HALF];
        #pragma unroll
        for (int mm = 0; mm < HALF; mm++) acc[mm] = make_float2(0.f, 0.f);
        int par = g & 1, gp = g >> 1;
        int off = par * (N/2);
        float2 wv = make_float2(1.f, 0.f);
        float2 wg = sW[2 * gp]; wg.y = -wg.y;
        for (int qp = 0; qp < N/2; qp++) {
            #pragma unroll
            for (int mm = 0; mm < HALF; mm++) {
                float2 v = sP1[(m0 + mm) * N + off + qp];
                acc[mm].x += v.x * wv.x - v.y * wv.y;
                acc[mm].y += v.x * wv.y + v.y * wv.x;
            }
            float nx = wv.x * wg.x - wv.y * wg.y;
            wv.y = wv.x * wg.y + wv.y * wg.x;
            wv.x = nx;
        }
        #pragma unroll
        for (int mm = 0; mm < HALF; mm++) sP1[(m0 + mm) * N + g] = acc[mm];
    }
    __syncthreads();
    if (g >= N) return;
    float2 P2f[ROWS];
    #pragma unroll
    for (int m = 0; m < ROWS; m++) P2f[m] = sP1[m * N + g];
    float* ob = act + ((long long)bo * N + j) * (N * N);
    int a0 = wave * (N / 4);
    for (int ap = 0; ap < N / 4; ap++) {
        int a = a0 + ap;
        float se = 0.f, so = 0.f;
        int t0 = 0;
        #pragma unroll
        for (int m = 1; m < ROWS; m++) {
            t0 += a; if (t0 >= N) t0 -= N;
            float vx = P2f[m].x + P2f[m].x;
            float vy = P2f[m].y + P2f[m].y;
            float2 w0 = sW[t0];
            float term = vx * w0.x + vy * w0.y;
            if (m & 1) so += term; else se += term;
        }
        float base = P2f[0].x;
        ob[a * N + g]           = fmaxf(base + se + so, 0.f);
        ob[(a + N/2) * N + g]   = fmaxf(base + se - so, 0.f);
    }
}

// ---------------- integrate + BN-MLP head (single block) --------------------
__global__ void head_kernel(const float* __restrict__ act, const float* __restrict__ wq,
    const float* __restrict__ g1, const float* __restrict__ be1,
    const float* __restrict__ w1, const float* __restrict__ b1,
    const float* __restrict__ g2, const float* __restrict__ be2,
    const float* __restrict__ w2, const float* __restrict__ b2,
    const float* __restrict__ g3, const float* __restrict__ be3,
    const float* __restrict__ w3, const float* __restrict__ b3,
    float* __restrict__ out)
{
    __shared__ float feat[512];
    __shared__ float xn[512];
    __shared__ float h1[512];
    __shared__ float h2[256];
    int tid = threadIdx.x;
    for (int t = tid; t < 512; t += blockDim.x) {
        int b = t >> 6, c = t & 63;
        const float* base = act + (size_t)(b*64 + c) * 216;
        float acc = 0.f;
        for (int j = 0; j < 6; j++) {
            float s = 0.f;
            for (int ag = 0; ag < 36; ag++) s += base[j*36 + ag];
            acc += wq[104 + j] * (s * (1.f / 36.f));
        }
        feat[t] = acc;
    }
    __syncthreads();
    for (int c = tid; c < 64; c += blockDim.x) {
        float mu = 0.f;
        for (int b = 0; b < 8; b++) mu += feat[b*64 + c];
        mu *= 0.125f;
        float var = 0.f;
        for (int b = 0; b < 8; b++) { float d = feat[b*64 + c] - mu; var += d*d; }
        var *= 0.125f;
        float is = rsqrtf(var + 1e-5f);
        for (int b = 0; b < 8; b++) xn[b*64 + c] = g1[c] * (feat[b*64 + c] - mu) * is + be1[c];
    }
    __syncthreads();
    for (int t = tid; t < 512; t += blockDim.x) {
        int b = t >> 6, o = t & 63;
        float acc = b1[o];
        for (int i = 0; i < 64; i++) acc += xn[b*64 + i] * w1[i*64 + o];
        h1[t] = fmaxf(acc, 0.f);
    }
    __syncthreads();
    for (int c = tid; c < 64; c += blockDim.x) {
        float mu = 0.f;
        for (int b = 0; b < 8; b++) mu += h1[b*64 + c];
        mu *= 0.125f;
        float var = 0.f;
        for (int b = 0; b < 8; b++) { float d = h1[b*64 + c] - mu; var += d*d; }
        var *= 0.125f;
        float is = rsqrtf(var + 1e-5f);
        for (int b = 0; b < 8; b++) xn[b*64 + c] = g2[c] * (h1[b*64 + c] - mu) * is + be2[c];
    }
    __syncthreads();
    for (int t = tid; t < 256; t += blockDim.x) {
        int b = t >> 5, o = t & 31;
        float acc = b2[o];
        for (int i = 0; i < 64; i++) acc += xn[b*64 + i] * w2[i*32 + o];
        h2[t] = fmaxf(acc, 0.f);
    }
    __syncthreads();
    for (int c = tid; c < 32; c += blockDim.x) {
        float mu = 0.f;
        for (int b = 0; b < 8; b++) mu += h2[b*32 + c];
        mu *= 0.125f;
        float var = 0.f;
        for (int b = 0; b < 8; b++) { float d = h2[b*32 + c] - mu; var += d*d; }
        var *= 0.125f;
        float is = rsqrtf(var + 1e-5f);
        for (int b = 0; b < 8; b++) xn[b*32 + c] = g3[c] * (h2[b*32 + c] - mu) * is + be3[c];
    }
    __syncthreads();
    for (int t = tid; t < 80; t += blockDim.x) {
        int b = t / 10, o = t % 10;
        float acc = b3[o];
        for (int i = 0; i < 32; i++) acc += xn[b*32 + i] * w3[i*10 + o];
        out[t] = acc;
    }
}

// ---------------------------------------------------------------------------

static inline int hmin(int a, int b) { return a < b ? a : b; }
static inline int hmax(int a, int b) { return a > b ? a : b; }
static inline int twoff(int N) { return N == 60 ? 0 : N == 30 ? 60 : N == 14 ? 90 : 104; }
static inline int wqoffb(int b) { return b == 30 ? 0 : b == 15 ? 60 : b == 7 ? 90 : 104; }

extern "C" void kernel_launch(void* const* d_in, const int* in_sizes, int n_in,
                              void* d_out, int out_size, void* d_ws, size_t ws_size,
                              hipStream_t stream)
{
    (void)in_sizes; (void)n_in; (void)out_size;
    const double PI = 3.14159265358979323846;
    struct LD { int kind, b_in, b_out, Ci, Co; double bg; };
    const LD LAY[7] = {
        {0, 30, 30,  1,  8, PI/16},
        {1, 30, 15,  8, 16, PI/16},
        {1, 15, 15, 16, 16, PI/8},
        {1, 15,  7, 16, 24, PI/8},
        {1,  7,  7, 24, 24, PI/4},
        {1,  7,  3, 24, 32, PI/4},
        {1,  3,  3, 32, 64, PI/2},
    };

    float* ws = (float*)d_ws;
    size_t off = 0;
    auto alloc = [&](size_t n) -> size_t { size_t o = off; off += (n + 63) & ~(size_t)63; return o; };
    size_t oA    = alloc(13400000);   // dft pass-1 out / Y buffer
    size_t oB    = alloc(8200000);    // dft pass-2 out
    size_t oAct1 = alloc(13824000);   // real activation ping
    size_t oAct2 = alloc(3456000);    // real activation pong
    size_t oXH   = alloc(1200000);
    size_t oZ    = alloc(4800000);
    size_t oWQ   = alloc(128);
    size_t oTW   = alloc(256);
    size_t oDin[7], oDout[7], oDg[7];
    for (int i = 0; i < 7; i++) {
        const LD& L = LAY[i];
        long long S = SF(L.b_out);
        bool reuse = (i == 2 || i == 4 || i == 6);   // din aliases prev dout
        if (reuse) {
            oDin[i]  = oDout[i-1];
            oDout[i] = oDout[i-1];
        } else {
            size_t din_sz = (L.kind == 0) ? (size_t)(2*L.b_in) * L.b_out * L.b_out
                                          : (size_t)(2*L.b_in) * S;
            oDin[i]  = alloc(din_sz);
            oDout[i] = alloc((size_t)(2*L.b_out) * S);
        }
        oDg[i]   = alloc((size_t)S);
    }
    if ((off + 64) * sizeof(float) > ws_size) return;

    float2* TW = (float2*)(ws + oTW);
    float*  WQ = ws + oWQ;

    setup_kernel<<<1, 128, 0, stream>>>(TW, WQ);

    // ---- ONE wigner launch for all tables ----
    WigCfg cfg;
    int ns = 0, totBlk = 0;
    auto addSeg = [&](int nblk, size_t o, int b_out, int colmode, int jmaj, int nb,
                      double b0, double bs) {
        cfg.nblk[ns] = nblk; cfg.off[ns] = (int)o; cfg.b_out[ns] = b_out;
        cfg.colmode[ns] = colmode; cfg.jmaj[ns] = jmaj; cfg.nb[ns] = nb;
        cfg.beta0[ns] = b0; cfg.bstep[ns] = bs;
        ns++; totBlk += nblk;
    };
    for (int i = 0; i < 7; i++) {
        const LD& L = LAY[i];
        bool reuse = (i == 2 || i == 4 || i == 6);
        if (!reuse) {
            // din: j-minor ([e][j]) for coalesced xh reads
            addSeg(2*L.b_in * L.b_out, oDin[i], L.b_out, (L.kind == 0) ? 1 : 0, 1,
                   2*L.b_in, PI/(4.0*L.b_in), PI/(2.0*L.b_in));
            // dout: j-major (synth reads whole row per j)
            addSeg(2*L.b_out * L.b_out, oDout[i], L.b_out, 0, 0,
                   2*L.b_out, PI/(4.0*L.b_out), PI/(2.0*L.b_out));
        }
        addSeg(L.b_out, oDg[i], L.b_out, 0, 0, 1, L.bg, 0.0);
    }
    cfg.nseg = ns;
    wigner_all_kernel<<<totBlk, 128, 0, stream>>>(ws, cfg);

    const int Bt = 8;
    const float* cur = (const float*)d_in[0];
    float* actbuf[2] = { ws + oAct1, ws + oAct2 };

    for (int i = 0; i < 7; i++) {
        const LD& L = LAY[i];
        int Nin = 2*L.b_in, Nout = 2*L.b_out, M = 2*L.b_out - 1;
        float2* A  = (float2*)(ws + oA);
        float2* Bb = (float2*)(ws + oB);
        float2* XH = (float2*)(ws + oXH);
        float2* Z  = (float2*)(ws + oZ);
        const float2* TWin  = TW + twoff(Nin);
        const float2* TWout = TW + twoff(Nout);
        const float*  wql   = WQ + wqoffb(L.b_in);
        const float*  kw    = (const float*)d_in[1 + i];
        float* actOut = actbuf[i & 1];
        bool reuse = (i == 2 || i == 4 || i == 6);
        // din addressing: own tables are j-minor; aliased tables are j-major
        int eMul = reuse ? 1 : Nin;
        int jMul = reuse ? (int)SF(L.b_out) : 1;

        if (L.kind == 0) {
            int R = Bt * L.Ci * Nin;
            int RPB = hmin(R, hmax(1, 2 * DFT_LDS / Nin));
            dft_r_kernel<<<(R + RPB - 1) / RPB, 256, 0, stream>>>(
                cur, Bb, TWin, R, Nin, L.b_out, RPB);
            int gx = (Bt * L.Ci * L.b_out + 255) / 256;
            xh_s2_kernel<<<dim3(gx, L.b_out), 256, 0, stream>>>(
                Bb, ws + oDin[i], wql, XH, Bt, L.Ci, Nin, L.b_out, eMul, jMul);
            int gz = (Bt * L.Co * L.b_out * M + 255) / 256;
            z_s2_direct<<<dim3(gz, L.b_out), 256, 0, stream>>>(
                XH, kw, ws + oDg[i], Z, Bt, L.Ci, L.Co, L.b_out);
        } else {
            int R1 = Bt * L.Ci * Nin * Nin;
            int RPB1 = hmin(R1, hmax(1, 2 * DFT_LDS / Nin));
            dft_r_kernel<<<(R1 + RPB1 - 1) / RPB1, 256, 0, stream>>>(
                cur, A, TWin, R1, Nin, L.b_out, RPB1);
            int R2 = Bt * L.Ci * Nin;
            int slab2 = Nin * L.b_out;
            int RPB2 = hmin(R2, hmax(1, DFT_LDS / slab2));
            dft2h_kernel<<<(R2 + RPB2 - 1) / RPB2, 256, 0, stream>>>(
                (const float2*)A, Bb, TWin, R2, Nin, L.b_out, RPB2);
            int gx = (Bt * L.Ci * L.b_out * M + 255) / 256;
            xh_so3_kernel<<<dim3(gx, L.b_out), 256, 0, stream>>>(
                Bb, ws + oDin[i], wql, XH, Bt, L.Ci, Nin, L.b_out, eMul, jMul);
            float2* Yb = (float2*)(ws + oA);
            int ty = L.Ci * M * L.Co * M;
            y_so3_direct<<<dim3((ty + 255) / 256, L.b_out), 256, 0, stream>>>(
                kw, ws + oDg[i], Yb, L.Ci, L.Co, L.b_out);
            int ntiles = (L.Co * M + 63) / 64;
            z_so3_gemm<<<dim3(ntiles, Bt, L.b_out), 256, 0, stream>>>(
                XH, Yb, Z, Bt, L.Ci, L.Co, L.b_out);
        }

        // fused Hermitian output synthesis
        int planes = Bt * L.Co * Nout;
        if (Nout == 60) {
            synth2_t<60,30,15><<<planes, 128, 0, stream>>>(Z, ws + oDout[i], TWout, actOut, planes);
        } else if (Nout == 30) {
            synth_t<30,15,32,2, 64><<<(planes + 1) / 2,  64, 0, stream>>>(Z, ws + oDout[i], TWout, actOut, planes);
        } else if (Nout == 14) {
            synth_t<14, 7,16,4, 64><<<(planes + 3) / 4,  64, 0, stream>>>(Z, ws + oDout[i], TWout, actOut, planes);
        } else {
            synth_t< 6, 3, 8,8, 64><<<(planes + 7) / 8,  64, 0, stream>>>(Z, ws + oDout[i], TWout, actOut, planes);
        }
        cur = actOut;
    }

    head_kernel<<<1, 256, 0, stream>>>(
        cur, WQ,
        (const float*)d_in[8],  (const float*)d_in[9],  (const float*)d_in[10], (const float*)d_in[11],
        (const float*)d_in[12], (const float*)d_in[13], (const float*)d_in[14], (const float*)d_in[15],
        (const float*)d_in[16], (const float*)d_in[17], (const float*)d_in[18], (const float*)d_in[19],
        (float*)d_out);
}

// Round 14
// 1572.552 us; speedup vs baseline: 1.4135x; 1.4135x over previous
//
#include <hip/hip_runtime.h>
#include <math.h>

// ---------------------------------------------------------------------------
// S2ConvNet_deep: 7 spectral conv layers (1 S2 + 6 SO3) + SO3-integrate + MLP.
// All constant tables computed on-device every call (graph-capture safe).
// R1: z_so3 as LDS-tiled complex GEMM.          R2: fused output synth.
// R3: Hermitian synth (m>=0 rows).              R4: register-resident P2.
// R5: streaming G-build + Hermitian input halving (m>=0 alpha freqs).
// R6: gamma-Hermitian dft2h.                    R8: dft_r real pass-1 DFT.
// R7: 2-wave synth (N=60).                      R9: radix-2 DIF + a-fold.
// R10: DIF+fold in synth_t; wigner dedup.       R11: 1 wigner launch; kf inline.
// R12 REVERTED: LDS atomicAdd G-build serialized (223->865us, VALU 16%).
//      LDS float atomics join float4-in-hot-loop on the never-again list.
//      KEPT: din j-minor layout (neutral).
// R13: synth4_t: 4 waves/plane (256T). G-build stride 256 w/ per-l barriers
//      (proven R9 form); q-pass rows split 8/8/8/6 across waves (acc[8]);
//      p-pass a-range split across waves. 32 waves/CU (was 20), per-wave
//      work halved.
// ---------------------------------------------------------------------------

#define DFT_LDS 3712   // float2 slots for DFT staging (29.7 KB)

__host__ __device__ inline long long SF(int l) { return (long long)l * (4LL*l*l - 1) / 3; }
__device__ inline int imod(int a, int n) { int r = a % n; return r < 0 ? r + n : r; }

// ---------------- Wigner small-d, ALL tables in one launch (fp64) -----------
struct WigCfg {
    int nseg;
    int nblk[16];
    int off[16];        // float offset into ws
    int b_out[16];
    int colmode[16];    // 1 = column m=0 only (S2 din), 0 = full
    int jmaj[16];       // 1 = store [e][j] (j-minor) for coalesced xh reads
    int nb[16];         // n_beta of segment
    double beta0[16];
    double bstep[16];
};

__global__ void wigner_all_kernel(float* __restrict__ ws, WigCfg cfg)
{
    __shared__ double lf[128];
    for (int t = threadIdx.x; t < 128; t += blockDim.x) lf[t] = lgamma((double)t + 1.0);
    __syncthreads();

    int b = blockIdx.x, s = 0;
    while (b >= cfg.nblk[s]) { b -= cfg.nblk[s]; s++; }
    float* out = ws + cfg.off[s];
    int b_out = cfg.b_out[s];
    int colmode = cfg.colmode[s];
    int jm = cfg.jmaj[s];
    int nb = cfg.nb[s];
    int l = b % b_out, j = b / b_out;
    double beta = cfg.beta0[s] + cfg.bstep[s] * j;

    double x  = cos(beta);
    double sb = sin(0.5 * beta);
    double cb = cos(0.5 * beta);
    double lsb = log(sb), lcb = log(cb);
    int dim = 2*l + 1;
    long long S  = SF(b_out);
    long long Ol = SF(l);
    long long b2 = (long long)b_out * b_out;
    int total = colmode ? dim : dim * dim;
    for (int t = threadIdx.x; t < total; t += blockDim.x) {
        int mi, ni;
        if (colmode) { mi = t; ni = l; }
        else         { mi = t / dim; ni = t % dim; }
        int mp = mi - l, mm = ni - l;
        int k1 = l + mm, k2 = l - mm, k3 = l + mp, k4 = l - mp;
        int kk = min(min(k1, k2), min(k3, k4));
        int a, lam;
        if      (kk == k1) { a = mp - mm; lam = mp - mm; }
        else if (kk == k2) { a = mm - mp; lam = 0; }
        else if (kk == k3) { a = mm - mp; lam = 0; }
        else               { a = mp - mm; lam = mp - mm; }
        int bb = 2*l - 2*kk - a;
        double lpref = 0.5 * (lf[2*l - kk] + lf[kk] - lf[kk + a] - lf[kk + bb]);
        double P = 1.0;
        if (kk >= 1) {
            double p0 = 1.0;
            double p1 = 0.5 * ((double)(a - bb) + (double)(a + bb + 2) * x);
            for (int n = 2; n <= kk; n++) {
                double c1 = 2.0*n*(n + a + bb)*(2.0*n + a + bb - 2.0);
                double c2 = (2.0*n + a + bb - 1.0) *
                            ((2.0*n + a + bb)*(2.0*n + a + bb - 2.0)*x + (double)(a*a) - (double)(bb*bb));
                double c3 = 2.0*(n + a - 1.0)*(n + bb - 1.0)*(2.0*n + a + bb);
                double pn = (c2*p1 - c3*p0) / c1;
                p0 = p1; p1 = pn;
            }
            P = p1;
        }
        double val = exp(lpref + (double)a * lsb + (double)bb * lcb) * P;
        if (lam & 1) val = -val;
        long long e = colmode ? ((long long)l*l + mi) : (Ol + (long long)mi * dim + ni);
        long long idx;
        if (jm) idx = e * nb + j;
        else    idx = colmode ? ((long long)j * b2 + e) : ((long long)j * S + e);
        out[idx] = (float)val;
    }
}

// ---------------- setup: twiddles + DH weights in one launch ----------------
__global__ void setup_kernel(float2* __restrict__ W, float* __restrict__ w)
{
    int t = threadIdx.x + blockIdx.x * blockDim.x;
    if (t >= 110) return;
    const int Ns[4]   = {60, 30, 14, 6};
    const int offs[4] = {0, 60, 90, 104};
    int si = (t < 60) ? 0 : (t < 90) ? 1 : (t < 104) ? 2 : 3;
    int N = Ns[si];
    int k = t - offs[si];
    double ang = -2.0 * M_PI * (double)k / (double)N;
    W[t] = make_float2((float)cos(ang), (float)sin(ang));
    int b = N / 2;
    double beta = M_PI * (2*k + 1) / (4.0 * b);
    double s = 0.0;
    for (int kk = 0; kk < b; kk++) s += sin((2*kk + 1) * beta) / (2*kk + 1);
    w[t] = (float)((2.0 / b) * sin(beta) * s);
}

// ---------------- real-input forward DFT: [R, N] reals -> [R, NF] ----------
__global__ void dft_r_kernel(const float* __restrict__ in, float2* __restrict__ out,
                             const float2* __restrict__ Wt,
                             int R, int N, int NF, int RPB)
{
    __shared__ float s[2 * DFT_LDS];
    __shared__ float2 sW[64];
    int r0 = blockIdx.x * RPB;
    if (r0 >= R) return;
    int nr = min(RPB, R - r0);
    for (int t = threadIdx.x; t < N; t += blockDim.x) sW[t] = Wt[t];
    for (int t = threadIdx.x; t < nr * N; t += blockDim.x)
        s[t] = in[(long long)r0 * N + t];
    __syncthreads();
    for (int t = threadIdx.x; t < nr * NF; t += blockDim.x) {
        int rr = t / NF, f = t % NF;
        const float* row = s + rr * N;
        float re = 0.f, im = 0.f;
        int tw = 0;
        for (int n = 0; n < N; n++) {
            float2 w = sW[tw];
            float v = row[n];
            re += v * w.x;
            im += v * w.y;
            tw += f; if (tw >= N) tw -= N;
        }
        out[(long long)(r0 + rr) * NF + f] = make_float2(re, im);
    }
}

// ---------------- pass-2 alpha DFT with Hermitian gamma reconstruction ------
__global__ void dft2h_kernel(const float2* __restrict__ in, float2* __restrict__ out,
                             const float2* __restrict__ Wt,
                             int R, int N, int C2, int RPB)
{
    __shared__ float2 s[DFT_LDS];
    __shared__ float2 sW[64];
    int r0 = blockIdx.x * RPB;
    if (r0 >= R) return;
    int nr = min(RPB, R - r0);
    int slab = N * C2;
    for (int t = threadIdx.x; t < N; t += blockDim.x) sW[t] = Wt[t];
    for (int t = threadIdx.x; t < nr * slab; t += blockDim.x)
        s[t] = in[(long long)r0 * slab + t];
    __syncthreads();
    int M = 2 * C2 - 1;
    int oslab = C2 * M;
    int work = C2 * C2;
    for (int t = threadIdx.x; t < nr * work; t += blockDim.x) {
        int rr = t / work, p = t % work;
        int m = p / C2, npos = p % C2;
        const float2* col = s + rr * slab + npos;
        float r1 = 0.f, i1 = 0.f, r2 = 0.f, i2 = 0.f;
        int tw = 0;
        for (int n = 0; n < N; n++) {
            float2 w = sW[tw];
            float2 v = col[n * C2];
            r1 += v.x * w.x - v.y * w.y;
            i1 += v.x * w.y + v.y * w.x;
            r2 += v.x * w.x + v.y * w.y;
            i2 += v.y * w.x - v.x * w.y;
            tw += m; if (tw >= N) tw -= N;
        }
        float2* ob = out + (long long)(r0 + rr) * oslab + (long long)m * M;
        ob[(C2 - 1) + npos] = make_float2(r1, i1);
        if (npos > 0) ob[(C2 - 1) - npos] = make_float2(r2, -i2);
    }
}

// ---------------- xh (Wigner analysis of input), rows mi >= l only ----------
__global__ void xh_so3_kernel(const float2* __restrict__ xf, const float* __restrict__ din,
                              const float* __restrict__ wq, float2* __restrict__ xh,
                              int B, int Ci, int Nin, int b_out, int eMul, int jMul)
{
    int l = blockIdx.y;
    int dim = 2*l + 1;
    int M = 2*b_out - 1;
    long long S = SF(b_out), Ol = SF(l);
    int rows = l + 1;
    int total = B * Ci * rows * dim;
    int idx = blockIdx.x * blockDim.x + threadIdx.x;
    if (idx >= total) return;
    int ni  = idx % dim;
    int mip = (idx / dim) % rows;
    int bc  = idx / (dim * rows);
    int mi  = mip + l;
    int mf  = mip;
    int nf  = ni - l + (b_out - 1);
    float re = 0.f, im = 0.f;
    const float2* xb = xf + ((long long)bc * Nin) * b_out * M + (long long)mf * M + nf;
    const float*  db = din + (Ol + (long long)mi * dim + ni) * eMul;
    for (int j = 0; j < Nin; j++) {
        float dv = db[(long long)j * jMul] * wq[j];
        float2 xv = xb[(long long)j * b_out * M];
        re += dv * xv.x; im += dv * xv.y;
    }
    xh[(long long)bc * S + Ol + (long long)mi * dim + ni] = make_float2(re, im);
}

__global__ void xh_s2_kernel(const float2* __restrict__ xf, const float* __restrict__ dincol,
                             const float* __restrict__ wq, float2* __restrict__ xh,
                             int B, int Ci, int Nin, int b_out, int eMul, int jMul)
{
    int l = blockIdx.y;
    int b2 = b_out * b_out;
    int rows = l + 1;
    int total = B * Ci * rows;
    int idx = blockIdx.x * blockDim.x + threadIdx.x;
    if (idx >= total) return;
    int mip = idx % rows;
    int bc  = idx / rows;
    int mi  = mip + l;
    int mf  = mip;
    const float* db = dincol + ((long long)l*l + mi) * eMul;
    float re = 0.f, im = 0.f;
    for (int j = 0; j < Nin; j++) {
        float dv = db[(long long)j * jMul] * wq[j];
        float2 xv = xf[((long long)bc * Nin + j) * b_out + mf];
        re += dv * xv.x; im += dv * xv.y;
    }
    xh[(long long)bc * b2 + (long long)l*l + mi] = make_float2(re, im);
}

// ---------------- Y = dg * kf (kf inlined): per l, [i][ki][o*dim+ni] --------
__global__ void y_so3_direct(const float* __restrict__ kw, const float* __restrict__ dg,
                             float2* __restrict__ Y, int Ci, int Co, int b_out)
{
    const float cr[6] = {1.f, .5f, -.5f, -1.f, -.5f, .5f};
    const float ci_[6] = {0.f, -0.8660254037844386f, -0.8660254037844386f, 0.f,
                          0.8660254037844386f, 0.8660254037844386f};
    int l = blockIdx.y;
    int dim = 2*l + 1;
    long long Ol = SF(l);
    int Nd = Co * dim;
    int total = Ci * dim * Nd;
    int idx = blockIdx.x * blockDim.x + threadIdx.x;
    if (idx >= total) return;
    int col  = idx % Nd;
    int krow = idx / Nd;
    int ki = krow % dim, i = krow / dim;
    int o  = col / dim,  ni = col % dim;
    float dgv = dg[Ol + (long long)ni * dim + ki];
    int m = ni - l, n = ki - l;
    const float* kb = kw + (long long)(i*Co + o) * 36;
    int step = imod(2 * n, 6);
    float re = 0.f, im = 0.f;
    for (int a = 0; a < 6; a++) {
        int tt = imod(a * (m - n), 6);
        #pragma unroll
        for (int g = 0; g < 6; g++) {
            float kv = kb[a*6 + g];
            re += kv * cr[tt]; im += kv * ci_[tt];
            tt += step; if (tt >= 6) tt -= 6;
        }
    }
    Y[(long long)Ci * Co * Ol + idx] = make_float2(dgv * re, dgv * im);
}

// ---------------- z = xh · conj(Y), rows mi >= l only -----------------------
__global__ void z_so3_gemm(const float2* __restrict__ xh, const float2* __restrict__ Y,
                           float2* __restrict__ z, int B, int Ci, int Co, int b_out)
{
    int l = blockIdx.z;
    int dim = 2*l + 1;
    int rows = l + 1;
    long long S = SF(b_out), Ol = SF(l);
    int Nd = Co * dim;
    int c0 = blockIdx.x * 64;
    if (c0 >= Nd) return;
    int b = blockIdx.y;
    int tid = threadIdx.x;
    int cc = tid & 63;
    int mg = tid >> 6;
    int col = c0 + cc;
    __shared__ float2 sA[32 * 29];
    __shared__ float2 sY[29 * 64];
    float2 acc[8];
    #pragma unroll
    for (int r = 0; r < 8; r++) acc[r] = make_float2(0.f, 0.f);
    const float2* Yl = Y + (long long)Ci * Co * Ol;
    int rd = rows * dim;
    for (int i = 0; i < Ci; i++) {
        const float2* Ab = xh + ((long long)(b*Ci + i)) * S + Ol + (long long)l * dim;
        for (int t = tid; t < 32 * dim; t += 256)
            sA[t] = (t < rd) ? Ab[t] : make_float2(0.f, 0.f);
        const float2* Yb = Yl + (long long)i * dim * Nd;
        for (int t = tid; t < dim * 64; t += 256) {
            int ki = t >> 6, c = t & 63;
            int gc = c0 + c;
            sY[t] = (gc < Nd) ? Yb[(long long)ki * Nd + gc] : make_float2(0.f, 0.f);
        }
        __syncthreads();
        for (int ki = 0; ki < dim; ki++) {
            float2 y = sY[ki*64 + cc];
            #pragma unroll
            for (int r = 0; r < 8; r++) {
                if (r*4 + mg < rows) {
                    float2 a = sA[(r*4 + mg) * dim + ki];
                    acc[r].x += a.x * y.x + a.y * y.y;
                    acc[r].y += a.y * y.x - a.x * y.y;
                }
            }
        }
        __syncthreads();
    }
    if (col < Nd) {
        int o = col / dim, ni = col % dim;
        long long base = ((long long)(b*Co + o)) * S + Ol + ni;
        #pragma unroll
        for (int r = 0; r < 8; r++) {
            int mip = r*4 + mg;
            if (mip < rows) z[base + (long long)(mip + l) * dim] = acc[r];
        }
    }
}

// ---------------- z for S2 layer (kf inlined, Ci small) ---------------------
__global__ void z_s2_direct(const float2* __restrict__ xh, const float* __restrict__ kw,
                            const float* __restrict__ dg, float2* __restrict__ z,
                            int B, int Ci, int Co, int b_out)
{
    const float cr[6] = {1.f, .5f, -.5f, -1.f, -.5f, .5f};
    const float ci_[6] = {0.f, -0.8660254037844386f, -0.8660254037844386f, 0.f,
                          0.8660254037844386f, 0.8660254037844386f};
    int l = blockIdx.y;
    int dim = 2*l + 1;
    int b2 = b_out * b_out;
    int rows = l + 1;
    long long S = SF(b_out), Ol = SF(l);
    int total = B * Co * rows * dim;
    int idx = blockIdx.x * blockDim.x + threadIdx.x;
    if (idx >= total) return;
    int ni  = idx % dim;
    int mip = (idx / dim) % rows;
    int o   = (idx / (dim * rows)) % Co;
    int b   = idx / (dim * rows * Co);
    int mi  = mip + l;
    float dgv = dg[Ol + (long long)ni * dim + l];
    int m = ni - l;
    int step = imod(m, 6);
    float sre = 0.f, sim = 0.f;
    for (int i = 0; i < Ci; i++) {
        const float* kb = kw + (long long)(i*Co + o) * 6;
        float kre = 0.f, kim = 0.f;
        int tt = 0;
        #pragma unroll
        for (int p = 0; p < 6; p++) {
            float kv = kb[p];
            kre += kv * cr[tt]; kim += kv * ci_[tt];
            tt += step; if (tt >= 6) tt -= 6;
        }
        float2 xv = xh[(long long)(b*Ci + i) * b2 + (long long)l*l + mi];
        sre += xv.x * kre + xv.y * kim;
        sim += xv.y * kre - xv.x * kim;
    }
    z[((long long)(b*Co + o)) * S + Ol + (long long)mi * dim + ni] = make_float2(dgv * sre, dgv * sim);
}

// ---------------- fused Hermitian output synthesis (R10: DIF+fold) ----------
template<int N, int ROWS, int GS, int PPB, int BLK>
__global__ __launch_bounds__(BLK) void synth_t(
    const float2* __restrict__ z, const float* __restrict__ dout,
    const float2* __restrict__ Wt, float* __restrict__ act, int nPlanes)
{
    __shared__ float2 sP1[PPB][ROWS * N];
    __shared__ float2 sW[N];
    int tid = threadIdx.x;
    for (int t = tid; t < N; t += BLK) sW[t] = Wt[t];
    int lane = tid & 63, wave = tid >> 6;
    int sub = lane / GS, g = lane - sub * GS;
    int lp = wave * (64 / GS) + sub;
    int P = blockIdx.x * PPB + lp;
    bool on = (P < nPlanes);
    int bo = on ? (P / N) : 0, j = on ? (P - (P / N) * N) : 0;
    long long S = SF(ROWS);
    const float* dj = dout + (long long)j * S;
    const float2* zb = z + (long long)bo * S;
    float2* P1 = sP1[lp];
    for (int t = g; t < ROWS * N; t += GS) P1[t] = make_float2(0.f, 0.f);
    if (on) {
        for (int l = 0; l < ROWS; l++) {
            int dim = 2*l + 1;
            int run = (l + 1) * dim;
            long long base = SF(l) + (long long)l * dim;
            float fdim = (float)dim;
            float rdim = 1.f / fdim;
            for (int s0 = 0; s0 < run; s0 += GS) {
                int s = s0 + g;
                if (s < run) {
                    int m = (int)((float)s * rdim);
                    int rem = s - m * dim;
                    if (rem < 0)         { m--; rem += dim; }
                    else if (rem >= dim) { m++; rem -= dim; }
                    int q = rem - l; if (q < 0) q += N;
                    long long e = base + s;
                    float dv = dj[e] * fdim;
                    float2 zv = zb[e];
                    float2 cur = P1[m * N + q];
                    cur.x += dv * zv.x; cur.y += dv * zv.y;
                    P1[m * N + q] = cur;
                }
            }
        }
    }
    __syncthreads();
    if (on) {
        for (int t = g; t < ROWS * (N/2); t += GS) {
            int mm = t / (N/2), qp = t - mm * (N/2);
            int row = mm * N;
            float2 a = P1[row + qp];
            float2 b = P1[row + qp + N/2];
            float2 w = sW[qp];
            float2 d = make_float2(a.x - b.x, a.y - b.y);
            P1[row + qp]       = make_float2(a.x + b.x, a.y + b.y);
            P1[row + qp + N/2] = make_float2(d.x * w.x + d.y * w.y,
                                             d.y * w.x - d.x * w.y);
        }
    }
    __syncthreads();
    float2 acc[ROWS];
    #pragma unroll
    for (int m = 0; m < ROWS; m++) acc[m] = make_float2(0.f, 0.f);
    bool act_ = on && (g < N);
    if (act_) {
        int par = g & 1, gp = g >> 1;
        int off = par * (N/2);
        float2 wv = make_float2(1.f, 0.f);
        float2 wg = sW[2 * gp]; wg.y = -wg.y;
        for (int qp = 0; qp < N/2; qp++) {
            #pragma unroll
            for (int m = 0; m < ROWS; m++) {
                float2 v = P1[m * N + off + qp];
                acc[m].x += v.x * wv.x - v.y * wv.y;
                acc[m].y += v.x * wv.y + v.y * wv.x;
            }
            float nx = wv.x * wg.x - wv.y * wg.y;
            wv.y = wv.x * wg.y + wv.y * wg.x;
            wv.x = nx;
        }
    }
    if (!act_) return;
    float* ob = act + ((long long)bo * N + j) * (N * N);
    for (int a = 0; a < N/2; a++) {
        float se = 0.f, so = 0.f;
        int t0 = 0;
        #pragma unroll
        for (int m = 1; m < ROWS; m++) {
            t0 += a; if (t0 >= N) t0 -= N;
            float vx = acc[m].x + acc[m].x;
            float vy = acc[m].y + acc[m].y;
            float2 w0 = sW[t0];
            float term = vx * w0.x + vy * w0.y;
            if (m & 1) so += term; else se += term;
        }
        float base = acc[0].x;
        ob[a * N + g]         = fmaxf(base + se + so, 0.f);
        ob[(a + N/2) * N + g] = fmaxf(base + se - so, 0.f);
    }
}

// ---------------- 4-wave synth for N=60 (R13) -------------------------------
// G-build over 256 threads with per-l barrier (proven R9 form). q-pass: wave
// w owns rows [8w, min(8w+8, ROWS)); p-pass: a in [8w, 8w+8) of [0, N/2).
template<int N, int ROWS>
__global__ __launch_bounds__(256) void synth4_t(
    const float2* __restrict__ z, const float* __restrict__ dout,
    const float2* __restrict__ Wt, float* __restrict__ act, int nPlanes)
{
    __shared__ float2 sP1[ROWS * N];
    __shared__ float2 sW[N];
    int tid = threadIdx.x;
    for (int t = tid; t < N; t += 256) sW[t] = Wt[t];
    int lane = tid & 63, wave = tid >> 6;      // wave in 0..3
    int g = lane;
    int P = blockIdx.x;
    if (P >= nPlanes) return;                  // block-uniform
    int bo = P / N, j = P - bo * N;
    long long S = SF(ROWS);
    const float* dj = dout + (long long)j * S;
    const float2* zb = z + (long long)bo * S;
    for (int t = tid; t < ROWS * N; t += 256) sP1[t] = make_float2(0.f, 0.f);
    __syncthreads();
    // ---- G build: all 256 threads, barrier per l ----
    for (int l = 0; l < ROWS; l++) {
        int dim = 2*l + 1;
        int run = (l + 1) * dim;
        long long base = SF(l) + (long long)l * dim;
        float fdim = (float)dim;
        float rdim = 1.f / fdim;
        for (int s0 = 0; s0 < run; s0 += 256) {
            int s = s0 + tid;
            if (s < run) {
                int m = (int)((float)s * rdim);
                int rem = s - m * dim;
                if (rem < 0)         { m--; rem += dim; }
                else if (rem >= dim) { m++; rem -= dim; }
                int q = rem - l; if (q < 0) q += N;
                long long e = base + s;
                float dv = dj[e] * fdim;
                float2 zv = zb[e];
                float2 cur = sP1[m * N + q];
                cur.x += dv * zv.x; cur.y += dv * zv.y;
                sP1[m * N + q] = cur;
            }
        }
        __syncthreads();
    }
    // ---- radix-2 DIF on own rows ----
    int m0 = wave * 8;
    int cnt = (ROWS - m0 < 8) ? (ROWS - m0) : 8;   // 8,8,8,6 for ROWS=30
    for (int t = lane; t < cnt * (N/2); t += 64) {
        int mm = t / (N/2), qp = t - mm * (N/2);
        int row = (m0 + mm) * N;
        float2 a = sP1[row + qp];
        float2 b = sP1[row + qp + N/2];
        float2 w = sW[qp];
        float2 d = make_float2(a.x - b.x, a.y - b.y);
        sP1[row + qp]       = make_float2(a.x + b.x, a.y + b.y);
        sP1[row + qp + N/2] = make_float2(d.x * w.x + d.y * w.y,
                                          d.y * w.x - d.x * w.y);
    }
    __syncthreads();
    // ---- q-pass: thread g, own rows only; parity-decomposed 30-pt DFT ----
    if (g < N) {
        float2 acc[8];
        #pragma unroll
        for (int mm = 0; mm < 8; mm++) acc[mm] = make_float2(0.f, 0.f);
        int par = g & 1, gp = g >> 1;
        int off = par * (N/2);
        float2 wv = make_float2(1.f, 0.f);
        float2 wg = sW[2 * gp]; wg.y = -wg.y;
        for (int qp = 0; qp < N/2; qp++) {
            #pragma unroll
            for (int mm = 0; mm < 8; mm++) {
                if (mm < cnt) {
                    float2 v = sP1[(m0 + mm) * N + off + qp];
                    acc[mm].x += v.x * wv.x - v.y * wv.y;
                    acc[mm].y += v.x * wv.y + v.y * wv.x;
                }
            }
            float nx = wv.x * wg.x - wv.y * wg.y;
            wv.y = wv.x * wg.y + wv.y * wg.x;
            wv.x = nx;
        }
        #pragma unroll
        for (int mm = 0; mm < 8; mm++)
            if (mm < cnt) sP1[(m0 + mm) * N + g] = acc[mm];
    }
    __syncthreads();
    if (g >= N) return;
    // ---- gather full column; folded p-pass over own a-range ----
    float2 P2f[ROWS];
    #pragma unroll
    for (int m = 0; m < ROWS; m++) P2f[m] = sP1[m * N + g];
    float* ob = act + ((long long)bo * N + j) * (N * N);
    for (int ap = 0; ap < 8; ap++) {
        int a = m0 + ap;
        if (a >= N/2) break;
        float se = 0.f, so = 0.f;
        int t0 = 0;
        #pragma unroll
        for (int m = 1; m < ROWS; m++) {
            t0 += a; if (t0 >= N) t0 -= N;
            float vx = P2f[m].x + P2f[m].x;
            float vy = P2f[m].y + P2f[m].y;
            float2 w0 = sW[t0];
            float term = vx * w0.x + vy * w0.y;
            if (m & 1) so += term; else se += term;
        }
        float base = P2f[0].x;
        ob[a * N + g]           = fmaxf(base + se + so, 0.f);
        ob[(a + N/2) * N + g]   = fmaxf(base + se - so, 0.f);
    }
}

// ---------------- integrate + BN-MLP head (single block) --------------------
__global__ void head_kernel(const float* __restrict__ act, const float* __restrict__ wq,
    const float* __restrict__ g1, const float* __restrict__ be1,
    const float* __restrict__ w1, const float* __restrict__ b1,
    const float* __restrict__ g2, const float* __restrict__ be2,
    const float* __restrict__ w2, const float* __restrict__ b2,
    const float* __restrict__ g3, const float* __restrict__ be3,
    const float* __restrict__ w3, const float* __restrict__ b3,
    float* __restrict__ out)
{
    __shared__ float feat[512];
    __shared__ float xn[512];
    __shared__ float h1[512];
    __shared__ float h2[256];
    int tid = threadIdx.x;
    for (int t = tid; t < 512; t += blockDim.x) {
        int b = t >> 6, c = t & 63;
        const float* base = act + (size_t)(b*64 + c) * 216;
        float acc = 0.f;
        for (int j = 0; j < 6; j++) {
            float s = 0.f;
            for (int ag = 0; ag < 36; ag++) s += base[j*36 + ag];
            acc += wq[104 + j] * (s * (1.f / 36.f));
        }
        feat[t] = acc;
    }
    __syncthreads();
    for (int c = tid; c < 64; c += blockDim.x) {
        float mu = 0.f;
        for (int b = 0; b < 8; b++) mu += feat[b*64 + c];
        mu *= 0.125f;
        float var = 0.f;
        for (int b = 0; b < 8; b++) { float d = feat[b*64 + c] - mu; var += d*d; }
        var *= 0.125f;
        float is = rsqrtf(var + 1e-5f);
        for (int b = 0; b < 8; b++) xn[b*64 + c] = g1[c] * (feat[b*64 + c] - mu) * is + be1[c];
    }
    __syncthreads();
    for (int t = tid; t < 512; t += blockDim.x) {
        int b = t >> 6, o = t & 63;
        float acc = b1[o];
        for (int i = 0; i < 64; i++) acc += xn[b*64 + i] * w1[i*64 + o];
        h1[t] = fmaxf(acc, 0.f);
    }
    __syncthreads();
    for (int c = tid; c < 64; c += blockDim.x) {
        float mu = 0.f;
        for (int b = 0; b < 8; b++) mu += h1[b*64 + c];
        mu *= 0.125f;
        float var = 0.f;
        for (int b = 0; b < 8; b++) { float d = h1[b*64 + c] - mu; var += d*d; }
        var *= 0.125f;
        float is = rsqrtf(var + 1e-5f);
        for (int b = 0; b < 8; b++) xn[b*64 + c] = g2[c] * (h1[b*64 + c] - mu) * is + be2[c];
    }
    __syncthreads();
    for (int t = tid; t < 256; t += blockDim.x) {
        int b = t >> 5, o = t & 31;
        float acc = b2[o];
        for (int i = 0; i < 64; i++) acc += xn[b*64 + i] * w2[i*32 + o];
        h2[t] = fmaxf(acc, 0.f);
    }
    __syncthreads();
    for (int c = tid; c < 32; c += blockDim.x) {
        float mu = 0.f;
        for (int b = 0; b < 8; b++) mu += h2[b*32 + c];
        mu *= 0.125f;
        float var = 0.f;
        for (int b = 0; b < 8; b++) { float d = h2[b*32 + c] - mu; var += d*d; }
        var *= 0.125f;
        float is = rsqrtf(var + 1e-5f);
        for (int b = 0; b < 8; b++) xn[b*32 + c] = g3[c] * (h2[b*32 + c] - mu) * is + be3[c];
    }
    __syncthreads();
    for (int t = tid; t < 80; t += blockDim.x) {
        int b = t / 10, o = t % 10;
        float acc = b3[o];
        for (int i = 0; i < 32; i++) acc += xn[b*32 + i] * w3[i*10 + o];
        out[t] = acc;
    }
}

// ---------------------------------------------------------------------------

static inline int hmin(int a, int b) { return a < b ? a : b; }
static inline int hmax(int a, int b) { return a > b ? a : b; }
static inline int twoff(int N) { return N == 60 ? 0 : N == 30 ? 60 : N == 14 ? 90 : 104; }
static inline int wqoffb(int b) { return b == 30 ? 0 : b == 15 ? 60 : b == 7 ? 90 : 104; }

extern "C" void kernel_launch(void* const* d_in, const int* in_sizes, int n_in,
                              void* d_out, int out_size, void* d_ws, size_t ws_size,
                              hipStream_t stream)
{
    (void)in_sizes; (void)n_in; (void)out_size;
    const double PI = 3.14159265358979323846;
    struct LD { int kind, b_in, b_out, Ci, Co; double bg; };
    const LD LAY[7] = {
        {0, 30, 30,  1,  8, PI/16},
        {1, 30, 15,  8, 16, PI/16},
        {1, 15, 15, 16, 16, PI/8},
        {1, 15,  7, 16, 24, PI/8},
        {1,  7,  7, 24, 24, PI/4},
        {1,  7,  3, 24, 32, PI/4},
        {1,  3,  3, 32, 64, PI/2},
    };

    float* ws = (float*)d_ws;
    size_t off = 0;
    auto alloc = [&](size_t n) -> size_t { size_t o = off; off += (n + 63) & ~(size_t)63; return o; };
    size_t oA    = alloc(13400000);   // dft pass-1 out / Y buffer
    size_t oB    = alloc(8200000);    // dft pass-2 out
    size_t oAct1 = alloc(13824000);   // real activation ping
    size_t oAct2 = alloc(3456000);    // real activation pong
    size_t oXH   = alloc(1200000);
    size_t oZ    = alloc(4800000);
    size_t oWQ   = alloc(128);
    size_t oTW   = alloc(256);
    size_t oDin[7], oDout[7], oDg[7];
    for (int i = 0; i < 7; i++) {
        const LD& L = LAY[i];
        long long S = SF(L.b_out);
        bool reuse = (i == 2 || i == 4 || i == 6);   // din aliases prev dout
        if (reuse) {
            oDin[i]  = oDout[i-1];
            oDout[i] = oDout[i-1];
        } else {
            size_t din_sz = (L.kind == 0) ? (size_t)(2*L.b_in) * L.b_out * L.b_out
                                          : (size_t)(2*L.b_in) * S;
            oDin[i]  = alloc(din_sz);
            oDout[i] = alloc((size_t)(2*L.b_out) * S);
        }
        oDg[i]   = alloc((size_t)S);
    }
    if ((off + 64) * sizeof(float) > ws_size) return;

    float2* TW = (float2*)(ws + oTW);
    float*  WQ = ws + oWQ;

    setup_kernel<<<1, 128, 0, stream>>>(TW, WQ);

    // ---- ONE wigner launch for all tables ----
    WigCfg cfg;
    int ns = 0, totBlk = 0;
    auto addSeg = [&](int nblk, size_t o, int b_out, int colmode, int jmaj, int nb,
                      double b0, double bs) {
        cfg.nblk[ns] = nblk; cfg.off[ns] = (int)o; cfg.b_out[ns] = b_out;
        cfg.colmode[ns] = colmode; cfg.jmaj[ns] = jmaj; cfg.nb[ns] = nb;
        cfg.beta0[ns] = b0; cfg.bstep[ns] = bs;
        ns++; totBlk += nblk;
    };
    for (int i = 0; i < 7; i++) {
        const LD& L = LAY[i];
        bool reuse = (i == 2 || i == 4 || i == 6);
        if (!reuse) {
            addSeg(2*L.b_in * L.b_out, oDin[i], L.b_out, (L.kind == 0) ? 1 : 0, 1,
                   2*L.b_in, PI/(4.0*L.b_in), PI/(2.0*L.b_in));
            addSeg(2*L.b_out * L.b_out, oDout[i], L.b_out, 0, 0,
                   2*L.b_out, PI/(4.0*L.b_out), PI/(2.0*L.b_out));
        }
        addSeg(L.b_out, oDg[i], L.b_out, 0, 0, 1, L.bg, 0.0);
    }
    cfg.nseg = ns;
    wigner_all_kernel<<<totBlk, 128, 0, stream>>>(ws, cfg);

    const int Bt = 8;
    const float* cur = (const float*)d_in[0];
    float* actbuf[2] = { ws + oAct1, ws + oAct2 };

    for (int i = 0; i < 7; i++) {
        const LD& L = LAY[i];
        int Nin = 2*L.b_in, Nout = 2*L.b_out, M = 2*L.b_out - 1;
        float2* A  = (float2*)(ws + oA);
        float2* Bb = (float2*)(ws + oB);
        float2* XH = (float2*)(ws + oXH);
        float2* Z  = (float2*)(ws + oZ);
        const float2* TWin  = TW + twoff(Nin);
        const float2* TWout = TW + twoff(Nout);
        const float*  wql   = WQ + wqoffb(L.b_in);
        const float*  kw    = (const float*)d_in[1 + i];
        float* actOut = actbuf[i & 1];
        bool reuse = (i == 2 || i == 4 || i == 6);
        int eMul = reuse ? 1 : Nin;
        int jMul = reuse ? (int)SF(L.b_out) : 1;

        if (L.kind == 0) {
            int R = Bt * L.Ci * Nin;
            int RPB = hmin(R, hmax(1, 2 * DFT_LDS / Nin));
            dft_r_kernel<<<(R + RPB - 1) / RPB, 256, 0, stream>>>(
                cur, Bb, TWin, R, Nin, L.b_out, RPB);
            int gx = (Bt * L.Ci * L.b_out + 255) / 256;
            xh_s2_kernel<<<dim3(gx, L.b_out), 256, 0, stream>>>(
                Bb, ws + oDin[i], wql, XH, Bt, L.Ci, Nin, L.b_out, eMul, jMul);
            int gz = (Bt * L.Co * L.b_out * M + 255) / 256;
            z_s2_direct<<<dim3(gz, L.b_out), 256, 0, stream>>>(
                XH, kw, ws + oDg[i], Z, Bt, L.Ci, L.Co, L.b_out);
        } else {
            int R1 = Bt * L.Ci * Nin * Nin;
            int RPB1 = hmin(R1, hmax(1, 2 * DFT_LDS / Nin));
            dft_r_kernel<<<(R1 + RPB1 - 1) / RPB1, 256, 0, stream>>>(
                cur, A, TWin, R1, Nin, L.b_out, RPB1);
            int R2 = Bt * L.Ci * Nin;
            int slab2 = Nin * L.b_out;
            int RPB2 = hmin(R2, hmax(1, DFT_LDS / slab2));
            dft2h_kernel<<<(R2 + RPB2 - 1) / RPB2, 256, 0, stream>>>(
                (const float2*)A, Bb, TWin, R2, Nin, L.b_out, RPB2);
            int gx = (Bt * L.Ci * L.b_out * M + 255) / 256;
            xh_so3_kernel<<<dim3(gx, L.b_out), 256, 0, stream>>>(
                Bb, ws + oDin[i], wql, XH, Bt, L.Ci, Nin, L.b_out, eMul, jMul);
            float2* Yb = (float2*)(ws + oA);
            int ty = L.Ci * M * L.Co * M;
            y_so3_direct<<<dim3((ty + 255) / 256, L.b_out), 256, 0, stream>>>(
                kw, ws + oDg[i], Yb, L.Ci, L.Co, L.b_out);
            int ntiles = (L.Co * M + 63) / 64;
            z_so3_gemm<<<dim3(ntiles, Bt, L.b_out), 256, 0, stream>>>(
                XH, Yb, Z, Bt, L.Ci, L.Co, L.b_out);
        }

        // fused Hermitian output synthesis
        int planes = Bt * L.Co * Nout;
        if (Nout == 60) {
            synth4_t<60,30><<<planes, 256, 0, stream>>>(Z, ws + oDout[i], TWout, actOut, planes);
        } else if (Nout == 30) {
            synth_t<30,15,32,2, 64><<<(planes + 1) / 2,  64, 0, stream>>>(Z, ws + oDout[i], TWout, actOut, planes);
        } else if (Nout == 14) {
            synth_t<14, 7,16,4, 64><<<(planes + 3) / 4,  64, 0, stream>>>(Z, ws + oDout[i], TWout, actOut, planes);
        } else {
            synth_t< 6, 3, 8,8, 64><<<(planes + 7) / 8,  64, 0, stream>>>(Z, ws + oDout[i], TWout, actOut, planes);
        }
        cur = actOut;
    }

    head_kernel<<<1, 256, 0, stream>>>(
        cur, WQ,
        (const float*)d_in[8],  (const float*)d_in[9],  (const float*)d_in[10], (const float*)d_in[11],
        (const float*)d_in[12], (const float*)d_in[13], (const float*)d_in[14], (const float*)d_in[15],
        (const float*)d_in[16], (const float*)d_in[17], (const float*)d_in[18], (const float*)d_in[19],
        (float*)d_out);
}

// Round 15
// 1468.742 us; speedup vs baseline: 1.5134x; 1.0707x over previous
//
#include <hip/hip_runtime.h>
#include <math.h>

// ---------------------------------------------------------------------------
// S2ConvNet_deep: 7 spectral conv layers (1 S2 + 6 SO3) + SO3-integrate + MLP.
// All constant tables computed on-device every call (graph-capture safe).
// R1: z_so3 as LDS-tiled complex GEMM.          R2: fused output synth.
// R3: Hermitian synth (m>=0 rows).              R4: register-resident P2.
// R5: streaming G-build + Hermitian input halving (m>=0 alpha freqs).
// R6: gamma-Hermitian dft2h.                    R8: dft_r real pass-1 DFT.
// R7/R13: multi-wave synth (N=60, now 4 waves). R9: radix-2 DIF + a-fold.
// R10: DIF+fold in synth_t; wigner dedup.       R11: 1 wigner launch; kf inline.
// R12 REVERTED: LDS atomicAdd G-build (serialized). KEPT: din j-minor.
// R14: fft2_kernel fuses gamma-DFT + Hermitian alpha-DFT per (b,ci,beta)
//      slab in LDS — kills the A-buffer HBM round-trip (~100 MB/call) and 6
//      dispatch drains. SPB slabs/block keeps grids >= ~1500.
// ---------------------------------------------------------------------------

#define DFT_LDS 3712   // float2 slots for DFT staging (29.7 KB)

__host__ __device__ inline long long SF(int l) { return (long long)l * (4LL*l*l - 1) / 3; }
__device__ inline int imod(int a, int n) { int r = a % n; return r < 0 ? r + n : r; }

// ---------------- Wigner small-d, ALL tables in one launch (fp64) -----------
struct WigCfg {
    int nseg;
    int nblk[16];
    int off[16];
    int b_out[16];
    int colmode[16];
    int jmaj[16];
    int nb[16];
    double beta0[16];
    double bstep[16];
};

__global__ void wigner_all_kernel(float* __restrict__ ws, WigCfg cfg)
{
    __shared__ double lf[128];
    for (int t = threadIdx.x; t < 128; t += blockDim.x) lf[t] = lgamma((double)t + 1.0);
    __syncthreads();

    int b = blockIdx.x, s = 0;
    while (b >= cfg.nblk[s]) { b -= cfg.nblk[s]; s++; }
    float* out = ws + cfg.off[s];
    int b_out = cfg.b_out[s];
    int colmode = cfg.colmode[s];
    int jm = cfg.jmaj[s];
    int nb = cfg.nb[s];
    int l = b % b_out, j = b / b_out;
    double beta = cfg.beta0[s] + cfg.bstep[s] * j;

    double x  = cos(beta);
    double sb = sin(0.5 * beta);
    double cb = cos(0.5 * beta);
    double lsb = log(sb), lcb = log(cb);
    int dim = 2*l + 1;
    long long S  = SF(b_out);
    long long Ol = SF(l);
    long long b2 = (long long)b_out * b_out;
    int total = colmode ? dim : dim * dim;
    for (int t = threadIdx.x; t < total; t += blockDim.x) {
        int mi, ni;
        if (colmode) { mi = t; ni = l; }
        else         { mi = t / dim; ni = t % dim; }
        int mp = mi - l, mm = ni - l;
        int k1 = l + mm, k2 = l - mm, k3 = l + mp, k4 = l - mp;
        int kk = min(min(k1, k2), min(k3, k4));
        int a, lam;
        if      (kk == k1) { a = mp - mm; lam = mp - mm; }
        else if (kk == k2) { a = mm - mp; lam = 0; }
        else if (kk == k3) { a = mm - mp; lam = 0; }
        else               { a = mp - mm; lam = mp - mm; }
        int bb = 2*l - 2*kk - a;
        double lpref = 0.5 * (lf[2*l - kk] + lf[kk] - lf[kk + a] - lf[kk + bb]);
        double P = 1.0;
        if (kk >= 1) {
            double p0 = 1.0;
            double p1 = 0.5 * ((double)(a - bb) + (double)(a + bb + 2) * x);
            for (int n = 2; n <= kk; n++) {
                double c1 = 2.0*n*(n + a + bb)*(2.0*n + a + bb - 2.0);
                double c2 = (2.0*n + a + bb - 1.0) *
                            ((2.0*n + a + bb)*(2.0*n + a + bb - 2.0)*x + (double)(a*a) - (double)(bb*bb));
                double c3 = 2.0*(n + a - 1.0)*(n + bb - 1.0)*(2.0*n + a + bb);
                double pn = (c2*p1 - c3*p0) / c1;
                p0 = p1; p1 = pn;
            }
            P = p1;
        }
        double val = exp(lpref + (double)a * lsb + (double)bb * lcb) * P;
        if (lam & 1) val = -val;
        long long e = colmode ? ((long long)l*l + mi) : (Ol + (long long)mi * dim + ni);
        long long idx;
        if (jm) idx = e * nb + j;
        else    idx = colmode ? ((long long)j * b2 + e) : ((long long)j * S + e);
        out[idx] = (float)val;
    }
}

// ---------------- setup: twiddles + DH weights in one launch ----------------
__global__ void setup_kernel(float2* __restrict__ W, float* __restrict__ w)
{
    int t = threadIdx.x + blockIdx.x * blockDim.x;
    if (t >= 110) return;
    const int Ns[4]   = {60, 30, 14, 6};
    const int offs[4] = {0, 60, 90, 104};
    int si = (t < 60) ? 0 : (t < 90) ? 1 : (t < 104) ? 2 : 3;
    int N = Ns[si];
    int k = t - offs[si];
    double ang = -2.0 * M_PI * (double)k / (double)N;
    W[t] = make_float2((float)cos(ang), (float)sin(ang));
    int b = N / 2;
    double beta = M_PI * (2*k + 1) / (4.0 * b);
    double s = 0.0;
    for (int kk = 0; kk < b; kk++) s += sin((2*kk + 1) * beta) / (2*kk + 1);
    w[t] = (float)((2.0 / b) * sin(beta) * s);
}

// ---------------- real-input forward DFT: [R, N] reals -> [R, NF] ----------
// (still used by the S2 layer's single alpha pass)
__global__ void dft_r_kernel(const float* __restrict__ in, float2* __restrict__ out,
                             const float2* __restrict__ Wt,
                             int R, int N, int NF, int RPB)
{
    __shared__ float s[2 * DFT_LDS];
    __shared__ float2 sW[64];
    int r0 = blockIdx.x * RPB;
    if (r0 >= R) return;
    int nr = min(RPB, R - r0);
    for (int t = threadIdx.x; t < N; t += blockDim.x) sW[t] = Wt[t];
    for (int t = threadIdx.x; t < nr * N; t += blockDim.x)
        s[t] = in[(long long)r0 * N + t];
    __syncthreads();
    for (int t = threadIdx.x; t < nr * NF; t += blockDim.x) {
        int rr = t / NF, f = t % NF;
        const float* row = s + rr * N;
        float re = 0.f, im = 0.f;
        int tw = 0;
        for (int n = 0; n < N; n++) {
            float2 w = sW[tw];
            float v = row[n];
            re += v * w.x;
            im += v * w.y;
            tw += f; if (tw >= N) tw -= N;
        }
        out[(long long)(r0 + rr) * NF + f] = make_float2(re, im);
    }
}

// ---------------- R14: fused 2-pass input FFT per (b,ci,beta) slab ----------
// in: [slab][alpha=N][gamma=N] real. Pass 1: gamma-DFT (n >= 0 only, real
// input). Pass 2: alpha-DFT with dual accumulation reconstructing +-n.
// out: [slab][m=0..C2-1][nf=0..2*C2-2], identical to old dft_r+dft2h chain.
__global__ void fft2_kernel(const float* __restrict__ in, float2* __restrict__ out,
                            const float2* __restrict__ Wt,
                            int R, int N, int C2, int SPB)
{
    extern __shared__ float sm[];
    float2* sW = (float2*)sm;                       // [N]
    float*  sIn = sm + 2 * N;                       // [SPB][N*N]
    float2* sMid = (float2*)(sIn + SPB * N * N);    // [SPB][N*C2]
    int tid = threadIdx.x;
    for (int t = tid; t < N; t += 256) sW[t] = Wt[t];
    int s0 = blockIdx.x * SPB;
    int ns = min(SPB, R - s0);
    if (ns <= 0) return;
    int slabIn = N * N;
    for (int t = tid; t < ns * slabIn; t += 256)
        sIn[t] = in[(long long)s0 * slabIn + t];
    __syncthreads();
    // ---- pass 1: gamma DFT, real input, n >= 0 ----
    int w1 = N * C2;
    for (int t = tid; t < ns * w1; t += 256) {
        int ss = t / w1, p = t - ss * w1;
        int a = p / C2, n = p - a * C2;
        const float* row = sIn + ss * slabIn + a * N;
        float re = 0.f, im = 0.f;
        int tw = 0;
        for (int g = 0; g < N; g++) {
            float2 w = sW[tw];
            float v = row[g];
            re += v * w.x;
            im += v * w.y;
            tw += n; if (tw >= N) tw -= N;
        }
        sMid[ss * w1 + a * C2 + n] = make_float2(re, im);
    }
    __syncthreads();
    // ---- pass 2: alpha DFT (m >= 0), dual accumulation for +-n ----
    int M = 2 * C2 - 1;
    int oslab = C2 * M;
    int w2 = C2 * C2;
    for (int t = tid; t < ns * w2; t += 256) {
        int ss = t / w2, p = t - ss * w2;
        int m = p / C2, npos = p - m * C2;
        const float2* col = sMid + ss * w1 + npos;
        float r1 = 0.f, i1 = 0.f, r2 = 0.f, i2 = 0.f;
        int tw = 0;
        for (int a = 0; a < N; a++) {
            float2 w = sW[tw];
            float2 v = col[a * C2];
            r1 += v.x * w.x - v.y * w.y;
            i1 += v.x * w.y + v.y * w.x;
            r2 += v.x * w.x + v.y * w.y;
            i2 += v.y * w.x - v.x * w.y;
            tw += m; if (tw >= N) tw -= N;
        }
        float2* ob = out + (long long)(s0 + ss) * oslab + (long long)m * M;
        ob[(C2 - 1) + npos] = make_float2(r1, i1);
        if (npos > 0) ob[(C2 - 1) - npos] = make_float2(r2, -i2);
    }
}

// ---------------- xh (Wigner analysis of input), rows mi >= l only ----------
__global__ void xh_so3_kernel(const float2* __restrict__ xf, const float* __restrict__ din,
                              const float* __restrict__ wq, float2* __restrict__ xh,
                              int B, int Ci, int Nin, int b_out, int eMul, int jMul)
{
    int l = blockIdx.y;
    int dim = 2*l + 1;
    int M = 2*b_out - 1;
    long long S = SF(b_out), Ol = SF(l);
    int rows = l + 1;
    int total = B * Ci * rows * dim;
    int idx = blockIdx.x * blockDim.x + threadIdx.x;
    if (idx >= total) return;
    int ni  = idx % dim;
    int mip = (idx / dim) % rows;
    int bc  = idx / (dim * rows);
    int mi  = mip + l;
    int mf  = mip;
    int nf  = ni - l + (b_out - 1);
    float re = 0.f, im = 0.f;
    const float2* xb = xf + ((long long)bc * Nin) * b_out * M + (long long)mf * M + nf;
    const float*  db = din + (Ol + (long long)mi * dim + ni) * eMul;
    for (int j = 0; j < Nin; j++) {
        float dv = db[(long long)j * jMul] * wq[j];
        float2 xv = xb[(long long)j * b_out * M];
        re += dv * xv.x; im += dv * xv.y;
    }
    xh[(long long)bc * S + Ol + (long long)mi * dim + ni] = make_float2(re, im);
}

__global__ void xh_s2_kernel(const float2* __restrict__ xf, const float* __restrict__ dincol,
                             const float* __restrict__ wq, float2* __restrict__ xh,
                             int B, int Ci, int Nin, int b_out, int eMul, int jMul)
{
    int l = blockIdx.y;
    int b2 = b_out * b_out;
    int rows = l + 1;
    int total = B * Ci * rows;
    int idx = blockIdx.x * blockDim.x + threadIdx.x;
    if (idx >= total) return;
    int mip = idx % rows;
    int bc  = idx / rows;
    int mi  = mip + l;
    int mf  = mip;
    const float* db = dincol + ((long long)l*l + mi) * eMul;
    float re = 0.f, im = 0.f;
    for (int j = 0; j < Nin; j++) {
        float dv = db[(long long)j * jMul] * wq[j];
        float2 xv = xf[((long long)bc * Nin + j) * b_out + mf];
        re += dv * xv.x; im += dv * xv.y;
    }
    xh[(long long)bc * b2 + (long long)l*l + mi] = make_float2(re, im);
}

// ---------------- Y = dg * kf (kf inlined): per l, [i][ki][o*dim+ni] --------
__global__ void y_so3_direct(const float* __restrict__ kw, const float* __restrict__ dg,
                             float2* __restrict__ Y, int Ci, int Co, int b_out)
{
    const float cr[6] = {1.f, .5f, -.5f, -1.f, -.5f, .5f};
    const float ci_[6] = {0.f, -0.8660254037844386f, -0.8660254037844386f, 0.f,
                          0.8660254037844386f, 0.8660254037844386f};
    int l = blockIdx.y;
    int dim = 2*l + 1;
    long long Ol = SF(l);
    int Nd = Co * dim;
    int total = Ci * dim * Nd;
    int idx = blockIdx.x * blockDim.x + threadIdx.x;
    if (idx >= total) return;
    int col  = idx % Nd;
    int krow = idx / Nd;
    int ki = krow % dim, i = krow / dim;
    int o  = col / dim,  ni = col % dim;
    float dgv = dg[Ol + (long long)ni * dim + ki];
    int m = ni - l, n = ki - l;
    const float* kb = kw + (long long)(i*Co + o) * 36;
    int step = imod(2 * n, 6);
    float re = 0.f, im = 0.f;
    for (int a = 0; a < 6; a++) {
        int tt = imod(a * (m - n), 6);
        #pragma unroll
        for (int g = 0; g < 6; g++) {
            float kv = kb[a*6 + g];
            re += kv * cr[tt]; im += kv * ci_[tt];
            tt += step; if (tt >= 6) tt -= 6;
        }
    }
    Y[(long long)Ci * Co * Ol + idx] = make_float2(dgv * re, dgv * im);
}

// ---------------- z = xh · conj(Y), rows mi >= l only -----------------------
__global__ void z_so3_gemm(const float2* __restrict__ xh, const float2* __restrict__ Y,
                           float2* __restrict__ z, int B, int Ci, int Co, int b_out)
{
    int l = blockIdx.z;
    int dim = 2*l + 1;
    int rows = l + 1;
    long long S = SF(b_out), Ol = SF(l);
    int Nd = Co * dim;
    int c0 = blockIdx.x * 64;
    if (c0 >= Nd) return;
    int b = blockIdx.y;
    int tid = threadIdx.x;
    int cc = tid & 63;
    int mg = tid >> 6;
    int col = c0 + cc;
    __shared__ float2 sA[32 * 29];
    __shared__ float2 sY[29 * 64];
    float2 acc[8];
    #pragma unroll
    for (int r = 0; r < 8; r++) acc[r] = make_float2(0.f, 0.f);
    const float2* Yl = Y + (long long)Ci * Co * Ol;
    int rd = rows * dim;
    for (int i = 0; i < Ci; i++) {
        const float2* Ab = xh + ((long long)(b*Ci + i)) * S + Ol + (long long)l * dim;
        for (int t = tid; t < 32 * dim; t += 256)
            sA[t] = (t < rd) ? Ab[t] : make_float2(0.f, 0.f);
        const float2* Yb = Yl + (long long)i * dim * Nd;
        for (int t = tid; t < dim * 64; t += 256) {
            int ki = t >> 6, c = t & 63;
            int gc = c0 + c;
            sY[t] = (gc < Nd) ? Yb[(long long)ki * Nd + gc] : make_float2(0.f, 0.f);
        }
        __syncthreads();
        for (int ki = 0; ki < dim; ki++) {
            float2 y = sY[ki*64 + cc];
            #pragma unroll
            for (int r = 0; r < 8; r++) {
                if (r*4 + mg < rows) {
                    float2 a = sA[(r*4 + mg) * dim + ki];
                    acc[r].x += a.x * y.x + a.y * y.y;
                    acc[r].y += a.y * y.x - a.x * y.y;
                }
            }
        }
        __syncthreads();
    }
    if (col < Nd) {
        int o = col / dim, ni = col % dim;
        long long base = ((long long)(b*Co + o)) * S + Ol + ni;
        #pragma unroll
        for (int r = 0; r < 8; r++) {
            int mip = r*4 + mg;
            if (mip < rows) z[base + (long long)(mip + l) * dim] = acc[r];
        }
    }
}

// ---------------- z for S2 layer (kf inlined, Ci small) ---------------------
__global__ void z_s2_direct(const float2* __restrict__ xh, const float* __restrict__ kw,
                            const float* __restrict__ dg, float2* __restrict__ z,
                            int B, int Ci, int Co, int b_out)
{
    const float cr[6] = {1.f, .5f, -.5f, -1.f, -.5f, .5f};
    const float ci_[6] = {0.f, -0.8660254037844386f, -0.8660254037844386f, 0.f,
                          0.8660254037844386f, 0.8660254037844386f};
    int l = blockIdx.y;
    int dim = 2*l + 1;
    int b2 = b_out * b_out;
    int rows = l + 1;
    long long S = SF(b_out), Ol = SF(l);
    int total = B * Co * rows * dim;
    int idx = blockIdx.x * blockDim.x + threadIdx.x;
    if (idx >= total) return;
    int ni  = idx % dim;
    int mip = (idx / dim) % rows;
    int o   = (idx / (dim * rows)) % Co;
    int b   = idx / (dim * rows * Co);
    int mi  = mip + l;
    float dgv = dg[Ol + (long long)ni * dim + l];
    int m = ni - l;
    int step = imod(m, 6);
    float sre = 0.f, sim = 0.f;
    for (int i = 0; i < Ci; i++) {
        const float* kb = kw + (long long)(i*Co + o) * 6;
        float kre = 0.f, kim = 0.f;
        int tt = 0;
        #pragma unroll
        for (int p = 0; p < 6; p++) {
            float kv = kb[p];
            kre += kv * cr[tt]; kim += kv * ci_[tt];
            tt += step; if (tt >= 6) tt -= 6;
        }
        float2 xv = xh[(long long)(b*Ci + i) * b2 + (long long)l*l + mi];
        sre += xv.x * kre + xv.y * kim;
        sim += xv.y * kre - xv.x * kim;
    }
    z[((long long)(b*Co + o)) * S + Ol + (long long)mi * dim + ni] = make_float2(dgv * sre, dgv * sim);
}

// ---------------- fused Hermitian output synthesis (R10: DIF+fold) ----------
template<int N, int ROWS, int GS, int PPB, int BLK>
__global__ __launch_bounds__(BLK) void synth_t(
    const float2* __restrict__ z, const float* __restrict__ dout,
    const float2* __restrict__ Wt, float* __restrict__ act, int nPlanes)
{
    __shared__ float2 sP1[PPB][ROWS * N];
    __shared__ float2 sW[N];
    int tid = threadIdx.x;
    for (int t = tid; t < N; t += BLK) sW[t] = Wt[t];
    int lane = tid & 63, wave = tid >> 6;
    int sub = lane / GS, g = lane - sub * GS;
    int lp = wave * (64 / GS) + sub;
    int P = blockIdx.x * PPB + lp;
    bool on = (P < nPlanes);
    int bo = on ? (P / N) : 0, j = on ? (P - (P / N) * N) : 0;
    long long S = SF(ROWS);
    const float* dj = dout + (long long)j * S;
    const float2* zb = z + (long long)bo * S;
    float2* P1 = sP1[lp];
    for (int t = g; t < ROWS * N; t += GS) P1[t] = make_float2(0.f, 0.f);
    if (on) {
        for (int l = 0; l < ROWS; l++) {
            int dim = 2*l + 1;
            int run = (l + 1) * dim;
            long long base = SF(l) + (long long)l * dim;
            float fdim = (float)dim;
            float rdim = 1.f / fdim;
            for (int s0 = 0; s0 < run; s0 += GS) {
                int s = s0 + g;
                if (s < run) {
                    int m = (int)((float)s * rdim);
                    int rem = s - m * dim;
                    if (rem < 0)         { m--; rem += dim; }
                    else if (rem >= dim) { m++; rem -= dim; }
                    int q = rem - l; if (q < 0) q += N;
                    long long e = base + s;
                    float dv = dj[e] * fdim;
                    float2 zv = zb[e];
                    float2 cur = P1[m * N + q];
                    cur.x += dv * zv.x; cur.y += dv * zv.y;
                    P1[m * N + q] = cur;
                }
            }
        }
    }
    __syncthreads();
    if (on) {
        for (int t = g; t < ROWS * (N/2); t += GS) {
            int mm = t / (N/2), qp = t - mm * (N/2);
            int row = mm * N;
            float2 a = P1[row + qp];
            float2 b = P1[row + qp + N/2];
            float2 w = sW[qp];
            float2 d = make_float2(a.x - b.x, a.y - b.y);
            P1[row + qp]       = make_float2(a.x + b.x, a.y + b.y);
            P1[row + qp + N/2] = make_float2(d.x * w.x + d.y * w.y,
                                             d.y * w.x - d.x * w.y);
        }
    }
    __syncthreads();
    float2 acc[ROWS];
    #pragma unroll
    for (int m = 0; m < ROWS; m++) acc[m] = make_float2(0.f, 0.f);
    bool act_ = on && (g < N);
    if (act_) {
        int par = g & 1, gp = g >> 1;
        int off = par * (N/2);
        float2 wv = make_float2(1.f, 0.f);
        float2 wg = sW[2 * gp]; wg.y = -wg.y;
        for (int qp = 0; qp < N/2; qp++) {
            #pragma unroll
            for (int m = 0; m < ROWS; m++) {
                float2 v = P1[m * N + off + qp];
                acc[m].x += v.x * wv.x - v.y * wv.y;
                acc[m].y += v.x * wv.y + v.y * wv.x;
            }
            float nx = wv.x * wg.x - wv.y * wg.y;
            wv.y = wv.x * wg.y + wv.y * wg.x;
            wv.x = nx;
        }
    }
    if (!act_) return;
    float* ob = act + ((long long)bo * N + j) * (N * N);
    for (int a = 0; a < N/2; a++) {
        float se = 0.f, so = 0.f;
        int t0 = 0;
        #pragma unroll
        for (int m = 1; m < ROWS; m++) {
            t0 += a; if (t0 >= N) t0 -= N;
            float vx = acc[m].x + acc[m].x;
            float vy = acc[m].y + acc[m].y;
            float2 w0 = sW[t0];
            float term = vx * w0.x + vy * w0.y;
            if (m & 1) so += term; else se += term;
        }
        float base = acc[0].x;
        ob[a * N + g]         = fmaxf(base + se + so, 0.f);
        ob[(a + N/2) * N + g] = fmaxf(base + se - so, 0.f);
    }
}

// ---------------- 4-wave synth for N=60 (R13) -------------------------------
template<int N, int ROWS>
__global__ __launch_bounds__(256) void synth4_t(
    const float2* __restrict__ z, const float* __restrict__ dout,
    const float2* __restrict__ Wt, float* __restrict__ act, int nPlanes)
{
    __shared__ float2 sP1[ROWS * N];
    __shared__ float2 sW[N];
    int tid = threadIdx.x;
    for (int t = tid; t < N; t += 256) sW[t] = Wt[t];
    int lane = tid & 63, wave = tid >> 6;
    int g = lane;
    int P = blockIdx.x;
    if (P >= nPlanes) return;
    int bo = P / N, j = P - bo * N;
    long long S = SF(ROWS);
    const float* dj = dout + (long long)j * S;
    const float2* zb = z + (long long)bo * S;
    for (int t = tid; t < ROWS * N; t += 256) sP1[t] = make_float2(0.f, 0.f);
    __syncthreads();
    for (int l = 0; l < ROWS; l++) {
        int dim = 2*l + 1;
        int run = (l + 1) * dim;
        long long base = SF(l) + (long long)l * dim;
        float fdim = (float)dim;
        float rdim = 1.f / fdim;
        for (int s0 = 0; s0 < run; s0 += 256) {
            int s = s0 + tid;
            if (s < run) {
                int m = (int)((float)s * rdim);
                int rem = s - m * dim;
                if (rem < 0)         { m--; rem += dim; }
                else if (rem >= dim) { m++; rem -= dim; }
                int q = rem - l; if (q < 0) q += N;
                long long e = base + s;
                float dv = dj[e] * fdim;
                float2 zv = zb[e];
                float2 cur = sP1[m * N + q];
                cur.x += dv * zv.x; cur.y += dv * zv.y;
                sP1[m * N + q] = cur;
            }
        }
        __syncthreads();
    }
    int m0 = wave * 8;
    int cnt = (ROWS - m0 < 8) ? (ROWS - m0) : 8;
    for (int t = lane; t < cnt * (N/2); t += 64) {
        int mm = t / (N/2), qp = t - mm * (N/2);
        int row = (m0 + mm) * N;
        float2 a = sP1[row + qp];
        float2 b = sP1[row + qp + N/2];
        float2 w = sW[qp];
        float2 d = make_float2(a.x - b.x, a.y - b.y);
        sP1[row + qp]       = make_float2(a.x + b.x, a.y + b.y);
        sP1[row + qp + N/2] = make_float2(d.x * w.x + d.y * w.y,
                                          d.y * w.x - d.x * w.y);
    }
    __syncthreads();
    if (g < N) {
        float2 acc[8];
        #pragma unroll
        for (int mm = 0; mm < 8; mm++) acc[mm] = make_float2(0.f, 0.f);
        int par = g & 1, gp = g >> 1;
        int off = par * (N/2);
        float2 wv = make_float2(1.f, 0.f);
        float2 wg = sW[2 * gp]; wg.y = -wg.y;
        for (int qp = 0; qp < N/2; qp++) {
            #pragma unroll
            for (int mm = 0; mm < 8; mm++) {
                if (mm < cnt) {
                    float2 v = sP1[(m0 + mm) * N + off + qp];
                    acc[mm].x += v.x * wv.x - v.y * wv.y;
                    acc[mm].y += v.x * wv.y + v.y * wv.x;
                }
            }
            float nx = wv.x * wg.x - wv.y * wg.y;
            wv.y = wv.x * wg.y + wv.y * wg.x;
            wv.x = nx;
        }
        #pragma unroll
        for (int mm = 0; mm < 8; mm++)
            if (mm < cnt) sP1[(m0 + mm) * N + g] = acc[mm];
    }
    __syncthreads();
    if (g >= N) return;
    float2 P2f[ROWS];
    #pragma unroll
    for (int m = 0; m < ROWS; m++) P2f[m] = sP1[m * N + g];
    float* ob = act + ((long long)bo * N + j) * (N * N);
    for (int ap = 0; ap < 8; ap++) {
        int a = m0 + ap;
        if (a >= N/2) break;
        float se = 0.f, so = 0.f;
        int t0 = 0;
        #pragma unroll
        for (int m = 1; m < ROWS; m++) {
            t0 += a; if (t0 >= N) t0 -= N;
            float vx = P2f[m].x + P2f[m].x;
            float vy = P2f[m].y + P2f[m].y;
            float2 w0 = sW[t0];
            float term = vx * w0.x + vy * w0.y;
            if (m & 1) so += term; else se += term;
        }
        float base = P2f[0].x;
        ob[a * N + g]           = fmaxf(base + se + so, 0.f);
        ob[(a + N/2) * N + g]   = fmaxf(base + se - so, 0.f);
    }
}

// ---------------- integrate + BN-MLP head (single block) --------------------
__global__ void head_kernel(const float* __restrict__ act, const float* __restrict__ wq,
    const float* __restrict__ g1, const float* __restrict__ be1,
    const float* __restrict__ w1, const float* __restrict__ b1,
    const float* __restrict__ g2, const float* __restrict__ be2,
    const float* __restrict__ w2, const float* __restrict__ b2,
    const float* __restrict__ g3, const float* __restrict__ be3,
    const float* __restrict__ w3, const float* __restrict__ b3,
    float* __restrict__ out)
{
    __shared__ float feat[512];
    __shared__ float xn[512];
    __shared__ float h1[512];
    __shared__ float h2[256];
    int tid = threadIdx.x;
    for (int t = tid; t < 512; t += blockDim.x) {
        int b = t >> 6, c = t & 63;
        const float* base = act + (size_t)(b*64 + c) * 216;
        float acc = 0.f;
        for (int j = 0; j < 6; j++) {
            float s = 0.f;
            for (int ag = 0; ag < 36; ag++) s += base[j*36 + ag];
            acc += wq[104 + j] * (s * (1.f / 36.f));
        }
        feat[t] = acc;
    }
    __syncthreads();
    for (int c = tid; c < 64; c += blockDim.x) {
        float mu = 0.f;
        for (int b = 0; b < 8; b++) mu += feat[b*64 + c];
        mu *= 0.125f;
        float var = 0.f;
        for (int b = 0; b < 8; b++) { float d = feat[b*64 + c] - mu; var += d*d; }
        var *= 0.125f;
        float is = rsqrtf(var + 1e-5f);
        for (int b = 0; b < 8; b++) xn[b*64 + c] = g1[c] * (feat[b*64 + c] - mu) * is + be1[c];
    }
    __syncthreads();
    for (int t = tid; t < 512; t += blockDim.x) {
        int b = t >> 6, o = t & 63;
        float acc = b1[o];
        for (int i = 0; i < 64; i++) acc += xn[b*64 + i] * w1[i*64 + o];
        h1[t] = fmaxf(acc, 0.f);
    }
    __syncthreads();
    for (int c = tid; c < 64; c += blockDim.x) {
        float mu = 0.f;
        for (int b = 0; b < 8; b++) mu += h1[b*64 + c];
        mu *= 0.125f;
        float var = 0.f;
        for (int b = 0; b < 8; b++) { float d = h1[b*64 + c] - mu; var += d*d; }
        var *= 0.125f;
        float is = rsqrtf(var + 1e-5f);
        for (int b = 0; b < 8; b++) xn[b*64 + c] = g2[c] * (h1[b*64 + c] - mu) * is + be2[c];
    }
    __syncthreads();
    for (int t = tid; t < 256; t += blockDim.x) {
        int b = t >> 5, o = t & 31;
        float acc = b2[o];
        for (int i = 0; i < 64; i++) acc += xn[b*64 + i] * w2[i*32 + o];
        h2[t] = fmaxf(acc, 0.f);
    }
    __syncthreads();
    for (int c = tid; c < 32; c += blockDim.x) {
        float mu = 0.f;
        for (int b = 0; b < 8; b++) mu += h2[b*32 + c];
        mu *= 0.125f;
        float var = 0.f;
        for (int b = 0; b < 8; b++) { float d = h2[b*32 + c] - mu; var += d*d; }
        var *= 0.125f;
        float is = rsqrtf(var + 1e-5f);
        for (int b = 0; b < 8; b++) xn[b*32 + c] = g3[c] * (h2[b*32 + c] - mu) * is + be3[c];
    }
    __syncthreads();
    for (int t = tid; t < 80; t += blockDim.x) {
        int b = t / 10, o = t % 10;
        float acc = b3[o];
        for (int i = 0; i < 32; i++) acc += xn[b*32 + i] * w3[i*10 + o];
        out[t] = acc;
    }
}

// ---------------------------------------------------------------------------

static inline int hmin(int a, int b) { return a < b ? a : b; }
static inline int hmax(int a, int b) { return a > b ? a : b; }
static inline int twoff(int N) { return N == 60 ? 0 : N == 30 ? 60 : N == 14 ? 90 : 104; }
static inline int wqoffb(int b) { return b == 30 ? 0 : b == 15 ? 60 : b == 7 ? 90 : 104; }

extern "C" void kernel_launch(void* const* d_in, const int* in_sizes, int n_in,
                              void* d_out, int out_size, void* d_ws, size_t ws_size,
                              hipStream_t stream)
{
    (void)in_sizes; (void)n_in; (void)out_size;
    const double PI = 3.14159265358979323846;
    struct LD { int kind, b_in, b_out, Ci, Co; double bg; };
    const LD LAY[7] = {
        {0, 30, 30,  1,  8, PI/16},
        {1, 30, 15,  8, 16, PI/16},
        {1, 15, 15, 16, 16, PI/8},
        {1, 15,  7, 16, 24, PI/8},
        {1,  7,  7, 24, 24, PI/4},
        {1,  7,  3, 24, 32, PI/4},
        {1,  3,  3, 32, 64, PI/2},
    };

    float* ws = (float*)d_ws;
    size_t off = 0;
    auto alloc = [&](size_t n) -> size_t { size_t o = off; off += (n + 63) & ~(size_t)63; return o; };
    size_t oA    = alloc(13400000);   // Y buffer
    size_t oB    = alloc(8200000);    // input spectrum
    size_t oAct1 = alloc(13824000);
    size_t oAct2 = alloc(3456000);
    size_t oXH   = alloc(1200000);
    size_t oZ    = alloc(4800000);
    size_t oWQ   = alloc(128);
    size_t oTW   = alloc(256);
    size_t oDin[7], oDout[7], oDg[7];
    for (int i = 0; i < 7; i++) {
        const LD& L = LAY[i];
        long long S = SF(L.b_out);
        bool reuse = (i == 2 || i == 4 || i == 6);
        if (reuse) {
            oDin[i]  = oDout[i-1];
            oDout[i] = oDout[i-1];
        } else {
            size_t din_sz = (L.kind == 0) ? (size_t)(2*L.b_in) * L.b_out * L.b_out
                                          : (size_t)(2*L.b_in) * S;
            oDin[i]  = alloc(din_sz);
            oDout[i] = alloc((size_t)(2*L.b_out) * S);
        }
        oDg[i]   = alloc((size_t)S);
    }
    if ((off + 64) * sizeof(float) > ws_size) return;

    float2* TW = (float2*)(ws + oTW);
    float*  WQ = ws + oWQ;

    setup_kernel<<<1, 128, 0, stream>>>(TW, WQ);

    WigCfg cfg;
    int ns = 0, totBlk = 0;
    auto addSeg = [&](int nblk, size_t o, int b_out, int colmode, int jmaj, int nb,
                      double b0, double bs) {
        cfg.nblk[ns] = nblk; cfg.off[ns] = (int)o; cfg.b_out[ns] = b_out;
        cfg.colmode[ns] = colmode; cfg.jmaj[ns] = jmaj; cfg.nb[ns] = nb;
        cfg.beta0[ns] = b0; cfg.bstep[ns] = bs;
        ns++; totBlk += nblk;
    };
    for (int i = 0; i < 7; i++) {
        const LD& L = LAY[i];
        bool reuse = (i == 2 || i == 4 || i == 6);
        if (!reuse) {
            addSeg(2*L.b_in * L.b_out, oDin[i], L.b_out, (L.kind == 0) ? 1 : 0, 1,
                   2*L.b_in, PI/(4.0*L.b_in), PI/(2.0*L.b_in));
            addSeg(2*L.b_out * L.b_out, oDout[i], L.b_out, 0, 0,
                   2*L.b_out, PI/(4.0*L.b_out), PI/(2.0*L.b_out));
        }
        addSeg(L.b_out, oDg[i], L.b_out, 0, 0, 1, L.bg, 0.0);
    }
    cfg.nseg = ns;
    wigner_all_kernel<<<totBlk, 128, 0, stream>>>(ws, cfg);

    const int Bt = 8;
    const float* cur = (const float*)d_in[0];
    float* actbuf[2] = { ws + oAct1, ws + oAct2 };

    for (int i = 0; i < 7; i++) {
        const LD& L = LAY[i];
        int Nin = 2*L.b_in, Nout = 2*L.b_out, M = 2*L.b_out - 1;
        float2* Bb = (float2*)(ws + oB);
        float2* XH = (float2*)(ws + oXH);
        float2* Z  = (float2*)(ws + oZ);
        const float2* TWin  = TW + twoff(Nin);
        const float2* TWout = TW + twoff(Nout);
        const float*  wql   = WQ + wqoffb(L.b_in);
        const float*  kw    = (const float*)d_in[1 + i];
        float* actOut = actbuf[i & 1];
        bool reuse = (i == 2 || i == 4 || i == 6);
        int eMul = reuse ? 1 : Nin;
        int jMul = reuse ? (int)SF(L.b_out) : 1;

        if (L.kind == 0) {
            int R = Bt * L.Ci * Nin;
            int RPB = hmin(R, hmax(1, 2 * DFT_LDS / Nin));
            dft_r_kernel<<<(R + RPB - 1) / RPB, 256, 0, stream>>>(
                cur, Bb, TWin, R, Nin, L.b_out, RPB);
            int gx = (Bt * L.Ci * L.b_out + 255) / 256;
            xh_s2_kernel<<<dim3(gx, L.b_out), 256, 0, stream>>>(
                Bb, ws + oDin[i], wql, XH, Bt, L.Ci, Nin, L.b_out, eMul, jMul);
            int gz = (Bt * L.Co * L.b_out * M + 255) / 256;
            z_s2_direct<<<dim3(gz, L.b_out), 256, 0, stream>>>(
                XH, kw, ws + oDg[i], Z, Bt, L.Ci, L.Co, L.b_out);
        } else {
            // fused 2-pass input FFT (gamma n>=0 + alpha dual +-n)
            int Rs = Bt * L.Ci * Nin;     // slabs of [alpha=Nin][gamma=Nin]
            int SPB = (Nin >= 60) ? 1 : (Nin >= 30) ? 2 : (Nin >= 14) ? 8 : 16;
            size_t lds = (size_t)Nin * sizeof(float2)
                       + (size_t)SPB * ((size_t)Nin * Nin * sizeof(float)
                                        + (size_t)Nin * L.b_out * sizeof(float2));
            fft2_kernel<<<(Rs + SPB - 1) / SPB, 256, lds, stream>>>(
                cur, Bb, TWin, Rs, Nin, L.b_out, SPB);
            int gx = (Bt * L.Ci * L.b_out * M + 255) / 256;
            xh_so3_kernel<<<dim3(gx, L.b_out), 256, 0, stream>>>(
                Bb, ws + oDin[i], wql, XH, Bt, L.Ci, Nin, L.b_out, eMul, jMul);
            float2* Yb = (float2*)(ws + oA);
            int ty = L.Ci * M * L.Co * M;
            y_so3_direct<<<dim3((ty + 255) / 256, L.b_out), 256, 0, stream>>>(
                kw, ws + oDg[i], Yb, L.Ci, L.Co, L.b_out);
            int ntiles = (L.Co * M + 63) / 64;
            z_so3_gemm<<<dim3(ntiles, Bt, L.b_out), 256, 0, stream>>>(
                XH, Yb, Z, Bt, L.Ci, L.Co, L.b_out);
        }

        int planes = Bt * L.Co * Nout;
        if (Nout == 60) {
            synth4_t<60,30><<<planes, 256, 0, stream>>>(Z, ws + oDout[i], TWout, actOut, planes);
        } else if (Nout == 30) {
            synth_t<30,15,32,2, 64><<<(planes + 1) / 2,  64, 0, stream>>>(Z, ws + oDout[i], TWout, actOut, planes);
        } else if (Nout == 14) {
            synth_t<14, 7,16,4, 64><<<(planes + 3) / 4,  64, 0, stream>>>(Z, ws + oDout[i], TWout, actOut, planes);
        } else {
            synth_t< 6, 3, 8,8, 64><<<(planes + 7) / 8,  64, 0, stream>>>(Z, ws + oDout[i], TWout, actOut, planes);
        }
        cur = actOut;
    }

    head_kernel<<<1, 256, 0, stream>>>(
        cur, WQ,
        (const float*)d_in[8],  (const float*)d_in[9],  (const float*)d_in[10], (const float*)d_in[11],
        (const float*)d_in[12], (const float*)d_in[13], (const float*)d_in[14], (const float*)d_in[15],
        (const float*)d_in[16], (const float*)d_in[17], (const float*)d_in[18], (const float*)d_in[19],
        (float*)d_out);
}